// Round 2
// baseline (694.658 us; speedup 1.0000x reference)
//
#include <hip/hip_runtime.h>
#include <hip/hip_bf16.h>

#define BB 128
#define LC 256
#define LE 1024
#define DD 256
#define MM 512

typedef short bf16x8 __attribute__((ext_vector_type(8)));
typedef unsigned short u16x8 __attribute__((ext_vector_type(8)));
typedef unsigned short u16x4 __attribute__((ext_vector_type(4)));
typedef float f32x4 __attribute__((ext_vector_type(4)));

__device__ __forceinline__ float bfu2f(unsigned short u) {
  return __uint_as_float(((unsigned int)u) << 16);
}
__device__ __forceinline__ unsigned short f2bfu(float f) {
  unsigned int x = __float_as_uint(f);
  return (unsigned short)((x + 0x7fffu + ((x >> 16) & 1u)) >> 16);
}

// LDS tile: rows x 32 k (u16), row stride 40 (80B = 20 banks).
// NO XOR: 5r mod 8 is a perfect permutation of the 8 16B-slot classes, so
// consecutive-row b128 reads and the stage writes are conflict-free as-is.
#define LDST 40
__device__ __forceinline__ int ldsoff(int r, int q) {
  return r * LDST + (q << 3);
}

// ---- shared MFMA inner step: 4 waves, each 64x64 = 4x4 tiles of 16x16x32 ----
__device__ __forceinline__ void mma_step(const unsigned short* As, const unsigned short* Bs,
                                         f32x4 (&acc)[4][4], int wm, int wn, int lane) {
  const int lm = lane & 15, quad = lane >> 4;
  bf16x8 a[4], b[4];
#pragma unroll
  for (int i = 0; i < 4; ++i) {
    int r = wm * 64 + i * 16 + lm;
    a[i] = *(const bf16x8*)&As[ldsoff(r, quad)];
    int n = wn * 64 + i * 16 + lm;
    b[i] = *(const bf16x8*)&Bs[ldsoff(n, quad)];
  }
#pragma unroll
  for (int i = 0; i < 4; ++i)
#pragma unroll
    for (int j = 0; j < 4; ++j)
      acc[i][j] = __builtin_amdgcn_mfma_f32_16x16x32_bf16(a[i], b[j], acc[i][j], 0, 0, 0);
}

// ---- generic MFMA tile step with independent row offsets ----
template <int MT, int NT>
__device__ __forceinline__ void mma_tiles(const unsigned short* As, const unsigned short* Bs,
                                          f32x4 (&acc)[MT][NT], int m0, int n0, int lane) {
  const int lm = lane & 15, quad = lane >> 4;
  bf16x8 a[MT], b[NT];
#pragma unroll
  for (int i = 0; i < MT; ++i)
    a[i] = *(const bf16x8*)&As[ldsoff(m0 + i * 16 + lm, quad)];
#pragma unroll
  for (int j = 0; j < NT; ++j)
    b[j] = *(const bf16x8*)&Bs[ldsoff(n0 + j * 16 + lm, quad)];
  __builtin_amdgcn_s_setprio(1);
#pragma unroll
  for (int i = 0; i < MT; ++i)
#pragma unroll
    for (int j = 0; j < NT; ++j)
      acc[i][j] = __builtin_amdgcn_mfma_f32_16x16x32_bf16(a[i], b[j], acc[i][j], 0, 0, 0);
  __builtin_amdgcn_s_setprio(0);
}

// ---- PV step: A from tight S4 chunk (128 rows x 32 k, swizzled), B via ldsoff ----
__device__ __forceinline__ void mma_pv(const unsigned short* S4c, const unsigned short* Bs,
                                       f32x4 (&acc)[4][4], int m0, int n0, int lane) {
  const int lm = lane & 15, quad = lane >> 4;
  bf16x8 a[4], b[4];
#pragma unroll
  for (int i = 0; i < 4; ++i) {
    int r = m0 + i * 16 + lm;
    a[i] = *(const bf16x8*)&S4c[r * 32 + ((quad ^ ((r >> 1) & 3)) << 3)];
    int n = n0 + i * 16 + lm;
    b[i] = *(const bf16x8*)&Bs[ldsoff(n, quad)];
  }
  __builtin_amdgcn_s_setprio(1);
#pragma unroll
  for (int i = 0; i < 4; ++i)
#pragma unroll
    for (int j = 0; j < 4; ++j)
      acc[i][j] = __builtin_amdgcn_mfma_f32_16x16x32_bf16(a[i], b[j], acc[i][j], 0, 0, 0);
  __builtin_amdgcn_s_setprio(0);
}

// ---- natural staging: bf16 source rows [r][k], 128x32 tile, 256 threads ----
__device__ __forceinline__ void stage_bf16(unsigned short* S, const unsigned short* g,
                                           long ld, int tid) {
#pragma unroll
  for (int i = 0; i < 2; ++i) {
    int c = tid + i * 256;
    int r = c >> 2, q = c & 3;
    u16x8 v = *(const u16x8*)(g + (long)r * ld + q * 8);
    *(u16x8*)&S[ldsoff(r, q)] = v;
  }
}

// ---- natural staging with fp32 -> bf16 convert (256 threads) ----
__device__ __forceinline__ void stage_f32(unsigned short* S, const float* g, long ld, int tid) {
#pragma unroll
  for (int i = 0; i < 2; ++i) {
    int c = tid + i * 256;
    int r = c >> 2, q = c & 3;
    const float4* p = (const float4*)(g + (long)r * ld + q * 8);
    float4 v0 = p[0], v1 = p[1];
    u16x8 o;
    o[0] = f2bfu(v0.x); o[1] = f2bfu(v0.y); o[2] = f2bfu(v0.z); o[3] = f2bfu(v0.w);
    o[4] = f2bfu(v1.x); o[5] = f2bfu(v1.y); o[6] = f2bfu(v1.z); o[7] = f2bfu(v1.w);
    *(u16x8*)&S[ldsoff(r, q)] = o;
  }
}

// ---- 512-thread staging: 128x32 bf16 tile in one shot ----
__device__ __forceinline__ void stage512(unsigned short* S, const unsigned short* g,
                                         long ld, int tid) {
  int r = tid >> 2, q = tid & 3;
  *(u16x8*)&S[ldsoff(r, q)] = *(const u16x8*)(g + (long)r * ld + q * 8);
}

// ---- 512-thread staging: 256x32 bf16 tile (two shots) ----
__device__ __forceinline__ void stage512x2(unsigned short* S, const unsigned short* g,
                                           long ld, int tid) {
#pragma unroll
  for (int it = 0; it < 2; ++it) {
    int c = tid + it * 512;
    int r = c >> 2, q = c & 3;
    *(u16x8*)&S[ldsoff(r, q)] = *(const u16x8*)(g + (long)r * ld + q * 8);
  }
}

// ---- zero fill ----
__global__ void zero_kernel(float* __restrict__ p, int n) {
  int i = blockIdx.x * 256 + threadIdx.x;
  if (i < n) p[i] = 0.f;
}

// ---- weight transpose+convert ----
__global__ void wconv_kernel(const float* __restrict__ Wa, const float* __restrict__ Wr,
                             unsigned short* __restrict__ WaT, unsigned short* __restrict__ WrT) {
  int i = blockIdx.x * 256 + threadIdx.x;
  if (i < 65536) WaT[i] = f2bfu(Wa[(i & 255) * 256 + (i >> 8)]);
  if (i < 131072) WrT[i] = f2bfu(Wr[(long)(i & 511) * 256 + (i >> 9)]);
}

// ---- fp32 [R][C] -> (a) mask-baked bf16 transpose dstT[C][R], (b) natural bf16 dstN[R][C] ----
__global__ void transT_kernel(const float* __restrict__ src, const int* __restrict__ mask,
                              unsigned short* __restrict__ dstT, unsigned short* __restrict__ dstN,
                              int R, int C) {
  __shared__ unsigned short T[64][72];
  const int tid = threadIdx.x, b = blockIdx.z;
  const int r0 = blockIdx.y * 64, c0 = blockIdx.x * 64;
  const float* s = src + (long)b * R * C;
  const int* mk = mask + (long)b * R;
  unsigned short* dT = dstT + (long)b * R * C;
  unsigned short* dN = dstN + (long)b * R * C;
#pragma unroll
  for (int i = 0; i < 4; ++i) {
    int r = (tid >> 4) + i * 16, c4 = tid & 15;
    float4 v = *(const float4*)(s + (long)(r0 + r) * C + c0 + c4 * 4);
    u16x4 nat;
    nat[0] = f2bfu(v.x); nat[1] = f2bfu(v.y); nat[2] = f2bfu(v.z); nat[3] = f2bfu(v.w);
    *(u16x4*)(dN + (long)(r0 + r) * C + c0 + c4 * 4) = nat;
    float g = mk[r0 + r] ? 1.f : 0.f;
    T[c4 * 4 + 0][r] = f2bfu(v.x * g);
    T[c4 * 4 + 1][r] = f2bfu(v.y * g);
    T[c4 * 4 + 2][r] = f2bfu(v.z * g);
    T[c4 * 4 + 3][r] = f2bfu(v.w * g);
  }
  __syncthreads();
#pragma unroll
  for (int j = 0; j < 2; ++j) {
    int idx = tid * 2 + j;
    int row = idx >> 3, ch = idx & 7;
    *(u16x8*)(dT + (long)(c0 + row) * R + r0 + ch * 8) = *(const u16x8*)&T[row][ch * 8];
  }
}

// ---- proj: out = relu(A @ Wa + ba) -> bf16 ----
__global__ __launch_bounds__(256, 2) void proj_mfma(const float* __restrict__ A,
                                                    const unsigned short* __restrict__ WaT,
                                                    const float* __restrict__ ba,
                                                    unsigned short* __restrict__ out) {
  __shared__ unsigned short As[128 * LDST], Bs[128 * LDST];
  const int tid = threadIdx.x, lane = tid & 63, w = tid >> 6, wm = w >> 1, wn = w & 1;
  const long m0 = (long)blockIdx.y * 128;
  const int n0 = blockIdx.x * 128;
  f32x4 acc[4][4] = {};
  for (int k0 = 0; k0 < DD; k0 += 32) {
    stage_f32(As, A + m0 * DD + k0, DD, tid);
    stage_bf16(Bs, WaT + (long)n0 * DD + k0, DD, tid);
    __syncthreads();
    mma_step(As, Bs, acc, wm, wn, lane);
    __syncthreads();
  }
  const int lm = lane & 15, quad = lane >> 4;
#pragma unroll
  for (int i = 0; i < 4; ++i)
#pragma unroll
    for (int j = 0; j < 4; ++j) {
      int col = n0 + wn * 64 + j * 16 + lm;
      float bias = ba[col];
#pragma unroll
      for (int r = 0; r < 4; ++r) {
        long row = m0 + wm * 64 + i * 16 + quad * 4 + r;
        float v = acc[i][j][r] + bias;
        out[row * DD + col] = f2bfu(v > 0.f ? v : 0.f);
      }
    }
}

// ============================================================================
// Merged fused attention. Both directions are the same computation:
//   out[tile_row][d] = (exp(aSrc @ resB^T)^T masked-normalized) @ pvB^T
// where resB = the 128-row tile owning the output rows, aSrc = the full
// contraction-side sequence (nch chunks of 128), mask applies to aSrc rows,
// pvB = [D][K] masked-transposed value matrix (K = nch*128).
//
// LDS (73,728 B -> 2 blocks/CU):
//   L[0..20480)  u16: staging. S-phase: slot p at p*10240 = {A(5120) | B(5120)};
//                PV-phase: slot p at p*10240 (256row x 32k). All double-buffered;
//                prefetch of {next S chunk | PV chunk0 | next-ch chunk0} always
//                overlaps the current MFMA phase (no cold stage+barrier pairs).
//   L[20480..36864) u16: S4 = 4 chunks x (128row x 32k) tight, XOR (r>>1)&3 on
//                16B slot: uniform banks for both 8B pack-writes and b128 reads.
//   asum aliases L[0..512B) after the last PV barrier.
// ============================================================================
__device__ void attn_body(unsigned short* L,
                          const unsigned short* resB, const unsigned short* aSrc,
                          const unsigned short* pvB, long pvLd, int nch,
                          const int* mask, unsigned short* outp, int tid) {
  const int lane = tid & 63, w = tid >> 6;
  const int lm = lane & 15, quad = lane >> 4;
  const int wmS = w >> 2, wnS = w & 3;  // S: A-side 64-half, out-row 32-quarter
  const int wm = w >> 2, wn = w & 3;    // PV: out-row 64-half, D 64-quarter
  unsigned short* S4 = L + 20480;
  float* asum_s = (float*)L;  // alias; only used after the final PV barrier
  f32x4 acc[4][4] = {};
  float ap0 = 0.f, ap1 = 0.f;
  // prologue: first S chunk pair into slot 0
  stage512(L, aSrc, DD, tid);
  stage512(L + 5120, resB, DD, tid);
  __syncthreads();
  for (int ch = 0; ch < nch; ++ch) {
    const unsigned short* Ag = aSrc + (long)ch * 128 * DD;
    f32x4 accS[4][2] = {};
    // ---- S phase: 8 k-steps, double-buffered ----
#pragma unroll
    for (int s = 0; s < 8; ++s) {
      if (s < 7) {
        unsigned short* d = L + ((s + 1) & 1) * 10240;
        stage512(d, Ag + (s + 1) * 32, DD, tid);
        stage512(d + 5120, resB + (s + 1) * 32, DD, tid);
      } else {
        // slot 0 free since step 6: prefetch PV chunk 0 (overlaps s=7 MFMA + pack)
        stage512x2(L, pvB + (long)ch * 128, pvLd, tid);
      }
      const unsigned short* base = L + (s & 1) * 10240;
      mma_tiles<4, 2>(base, base + 5120, accS, wmS * 64, wnS * 32, lane);
      __syncthreads();
    }
    // ---- exp + pack into S4 + masked denominator partials ----
#pragma unroll
    for (int i = 0; i < 4; ++i) {
      const int A0 = wmS * 64 + i * 16 + quad * 4;  // contraction index in chunk
      const int4 m4 = *(const int4*)(mask + ch * 128 + A0);
      const float g0 = m4.x ? 1.f : 0.f, g1 = m4.y ? 1.f : 0.f;
      const float g2 = m4.z ? 1.f : 0.f, g3 = m4.w ? 1.f : 0.f;
      const int kk = A0 >> 5, wi = A0 & 31;
      const int qq = wi >> 3, sub = wi & 7;  // sub in {0,4}: 8B aligned
#pragma unroll
      for (int j = 0; j < 2; ++j) {
        const int row = wnS * 32 + j * 16 + lm;  // output row in tile
        float e0 = __expf(accS[i][j][0]);
        float e1 = __expf(accS[i][j][1]);
        float e2 = __expf(accS[i][j][2]);
        float e3 = __expf(accS[i][j][3]);
        float sm = g0 * e0 + g1 * e1 + g2 * e2 + g3 * e3;
        if (j == 0) ap0 += sm; else ap1 += sm;
        u16x4 pk;
        pk[0] = f2bfu(e0); pk[1] = f2bfu(e1); pk[2] = f2bfu(e2); pk[3] = f2bfu(e3);
        *(u16x4*)&S4[kk * 4096 + row * 32 + ((qq ^ ((row >> 1) & 3)) << 3) + sub] = pk;
      }
    }
    __syncthreads();
    // ---- PV phase: 4 k-steps, double-buffered ----
#pragma unroll
    for (int kk = 0; kk < 4; ++kk) {
      if (kk < 3) {
        stage512x2(L + ((kk + 1) & 1) * 10240, pvB + (long)ch * 128 + (kk + 1) * 32, pvLd, tid);
      } else if (ch + 1 < nch) {
        // slot 0 free since kk=2: prefetch next ch's first S chunk pair
        stage512(L, aSrc + (long)(ch + 1) * 128 * DD, DD, tid);
        stage512(L + 5120, resB, DD, tid);
      }
      mma_pv(S4 + kk * 4096, L + (kk & 1) * 10240, acc, wm * 64, wn * 64, lane);
      __syncthreads();
    }
  }
  // ---- block-local softmax denominators for the 128 output rows ----
  if (tid < 128) asum_s[tid] = 0.f;
  __syncthreads();
  {
    float s = ap0;
    s += __shfl_xor(s, 16); s += __shfl_xor(s, 32);
    if (quad == 0) atomicAdd(&asum_s[wnS * 32 + lm], s);
    float t = ap1;
    t += __shfl_xor(t, 16); t += __shfl_xor(t, 32);
    if (quad == 0) atomicAdd(&asum_s[wnS * 32 + 16 + lm], t);
  }
  __syncthreads();
  float rs[4][4];
#pragma unroll
  for (int i = 0; i < 4; ++i)
#pragma unroll
    for (int r = 0; r < 4; ++r)
      rs[i][r] = 1.f / asum_s[wm * 64 + i * 16 + quad * 4 + r];
#pragma unroll
  for (int i = 0; i < 4; ++i)
#pragma unroll
    for (int j = 0; j < 4; ++j) {
      int col = wn * 64 + j * 16 + lm;
#pragma unroll
      for (int r = 0; r < 4; ++r) {
        int row = wm * 64 + i * 16 + quad * 4 + r;
        outp[(long)row * DD + col] = f2bfu(acc[i][j][r] * rs[i][r]);
      }
    }
}

__global__ __launch_bounds__(512, 2) void attn_fused(
    const unsigned short* __restrict__ cB, const unsigned short* __restrict__ eB,
    const unsigned short* __restrict__ ehrTm, const unsigned short* __restrict__ critTm,
    const int* __restrict__ em, const int* __restrict__ cm,
    unsigned short* __restrict__ attc, unsigned short* __restrict__ atte) {
  __shared__ unsigned short L[36864];
  const int tid = threadIdx.x, fid = blockIdx.x;
  if (fid < 256) {
    // criteria-side (4x work per block -> dispatched first for backfill balance)
    const int lid = (fid & 7) * 32 + (fid >> 3);  // XCD-bijective: b pairs share L2
    const int b = lid >> 1, m0 = (lid & 1) * 128;
    attn_body(L, cB + ((long)b * LC + m0) * DD, eB + (long)b * LE * DD,
              ehrTm + (long)b * DD * LE, LE, 8, em + (long)b * LE,
              attc + ((long)b * LC + m0) * DD, tid);
  } else {
    const int f = fid - 256;
    const int lid = (f & 7) * 128 + (f >> 3);  // same b->XCD mapping as c-side
    const int b = lid >> 3, n0 = (lid & 7) * 128;
    attn_body(L, eB + ((long)b * LE + n0) * DD, cB + (long)b * LC * DD,
              critTm + (long)b * DD * LC, LC, 2, cm + (long)b * LC,
              atte + ((long)b * LE + n0) * DD, tid);
  }
}

// ---- r = sum_seq relu([att | origB] @ Wr + br), all-bf16 staging ----
__global__ __launch_bounds__(256, 2) void rsum_mfma(const unsigned short* __restrict__ att,
                                                    const unsigned short* __restrict__ origB,
                                                    const unsigned short* __restrict__ WrT,
                                                    const float* __restrict__ br,
                                                    float* __restrict__ rout, int Lseq) {
  __shared__ unsigned short As[128 * LDST], Bs[128 * LDST];
  __shared__ float red[2][128];
  const int tid = threadIdx.x, lane = tid & 63, w = tid >> 6, wm = w >> 1, wn = w & 1;
  const long m0 = (long)blockIdx.y * 128;
  const int n0 = blockIdx.x * 128;
  const int b = (int)(m0 / Lseq);
  f32x4 acc[4][4] = {};
  for (int k0 = 0; k0 < 2 * DD; k0 += 32) {
    if (k0 < DD)
      stage_bf16(As, att + m0 * DD + k0, DD, tid);
    else
      stage_bf16(As, origB + m0 * DD + (k0 - DD), DD, tid);
    stage_bf16(Bs, WrT + (long)n0 * (2 * DD) + k0, 2 * DD, tid);
    __syncthreads();
    mma_step(As, Bs, acc, wm, wn, lane);
    __syncthreads();
  }
  const int lm = lane & 15, quad = lane >> 4;
#pragma unroll
  for (int j = 0; j < 4; ++j) {
    int col = n0 + wn * 64 + j * 16 + lm;
    float bias = br[col];
    float s = 0.f;
#pragma unroll
    for (int i = 0; i < 4; ++i)
#pragma unroll
      for (int r = 0; r < 4; ++r) {
        float v = acc[i][j][r] + bias;
        s += v > 0.f ? v : 0.f;
      }
    s += __shfl_xor(s, 16);
    s += __shfl_xor(s, 32);
    if (quad == 0) red[wm][wn * 64 + j * 16 + lm] = s;
  }
  __syncthreads();
  if (tid < 128)
    atomicAdd(&rout[b * DD + n0 + tid], red[0][tid] + red[1][tid]);
}

// ---- build m = [r1 | r2 | r1*r2 | r1-r2] as bf16 [128][1024] ----
__global__ void mbuild_kernel(const float* __restrict__ r1, const float* __restrict__ r2,
                              unsigned short* __restrict__ mB) {
  int i = blockIdx.x * 256 + threadIdx.x;
  int b = i >> 8, d = i & 255;
  float v1 = r1[i], v2 = r2[i];
  unsigned short* row = mB + (long)b * 1024;
  row[d] = f2bfu(v1);
  row[256 + d] = f2bfu(v2);
  row[512 + d] = f2bfu(v1 * v2);
  row[768 + d] = f2bfu(v1 - v2);
}

// ---- h = relu(m @ Wm + bm): M=128, N=512, K=1024 MFMA GEMM ----
__global__ __launch_bounds__(256, 2) void mlp_mfma(const unsigned short* __restrict__ mB,
                                                   const float* __restrict__ Wm,
                                                   const float* __restrict__ bm,
                                                   float* __restrict__ h) {
  __shared__ unsigned short As[128 * LDST], Bs[128 * LDST];
  const int tid = threadIdx.x, lane = tid & 63, w = tid >> 6, wm = w >> 1, wn = w & 1;
  const int n0 = blockIdx.x * 128;
  f32x4 acc[4][4] = {};
  for (int k0 = 0; k0 < 4 * DD; k0 += 32) {
    stage_bf16(As, mB + k0, 4 * DD, tid);
    {
      const int dcc = tid & 7, er = tid >> 3;
#pragma unroll
      for (int i = 0; i < 4; ++i) {
        int nch = dcc + i * 8;
        float4 v = *(const float4*)(Wm + (long)(k0 + er) * MM + n0 + nch * 4);
        float vv[4] = {v.x, v.y, v.z, v.w};
#pragma unroll
        for (int q = 0; q < 4; ++q)
          Bs[ldsoff(nch * 4 + q, er >> 3) + (er & 7)] = f2bfu(vv[q]);
      }
    }
    __syncthreads();
    mma_step(As, Bs, acc, wm, wn, lane);
    __syncthreads();
  }
  const int lm = lane & 15, quad = lane >> 4;
#pragma unroll
  for (int i = 0; i < 4; ++i)
#pragma unroll
    for (int j = 0; j < 4; ++j) {
      int col = n0 + wn * 64 + j * 16 + lm;
      float bias = bm[col];
#pragma unroll
      for (int r = 0; r < 4; ++r) {
        int row = wm * 64 + i * 16 + quad * 4 + r;
        float v = acc[i][j][r] + bias;
        h[(long)row * MM + col] = v > 0.f ? v : 0.f;
      }
    }
}

// ---- out = h @ Wo + bo ----
__global__ void out3_kernel(const float* __restrict__ h, const float* __restrict__ Wo,
                            const float* __restrict__ bo, float* __restrict__ out) {
  const int b = blockIdx.x, tid = threadIdx.x;
  __shared__ float red[256];
  float a[3] = {0.f, 0.f, 0.f};
  for (int k = tid; k < MM; k += 256) {
    float hv = h[(long)b * MM + k];
    a[0] += hv * Wo[k * 3 + 0];
    a[1] += hv * Wo[k * 3 + 1];
    a[2] += hv * Wo[k * 3 + 2];
  }
#pragma unroll
  for (int o = 0; o < 3; ++o) {
    red[tid] = a[o]; __syncthreads();
    for (int st = 128; st > 0; st >>= 1) {
      if (tid < st) red[tid] += red[tid + st];
      __syncthreads();
    }
    if (tid == 0) out[b * 3 + o] = red[0] + bo[o];
    __syncthreads();
  }
}

extern "C" void kernel_launch(void* const* d_in, const int* in_sizes, int n_in,
                              void* d_out, int out_size, void* d_ws, size_t ws_size,
                              hipStream_t stream) {
  const float* criteria = (const float*)d_in[0];
  const float* ehr      = (const float*)d_in[1];
  const int*   cmask    = (const int*)d_in[2];
  const int*   emask    = (const int*)d_in[3];
  const float* Wa       = (const float*)d_in[4];
  const float* ba       = (const float*)d_in[5];
  const float* Wr       = (const float*)d_in[6];
  const float* br       = (const float*)d_in[7];
  const float* Wm       = (const float*)d_in[8];
  const float* bm       = (const float*)d_in[9];
  const float* Wo       = (const float*)d_in[10];
  const float* bo       = (const float*)d_in[11];
  float* out = (float*)d_out;

  char* ws = (char*)d_ws;
  unsigned short* cB     = (unsigned short*)(ws);               // 16.78 MB
  unsigned short* eB     = (unsigned short*)(ws + 16777216);    // 67.1 MB
  unsigned short* ehrTm  = (unsigned short*)(ws + 83886080);    // 67.1 MB, em-masked ehr^T
  unsigned short* critTm = (unsigned short*)(ws + 150994944);   // 16.78 MB, cm-masked crit^T
  unsigned short* ehrN   = (unsigned short*)(ws + 167772160);   // 67.1 MB natural bf16 ehr
  unsigned short* critN  = (unsigned short*)(ws + 234881024);   // 16.78 MB natural bf16 crit
  unsigned short* attc   = (unsigned short*)(ws + 251658240);   // 16.78 MB
  unsigned short* atteP  = (unsigned short*)(ws + 268435456);   // 67.1 MB
  float* r1   = (float*)(ws + 335544320);                       // 131072 B
  float* r2   = (float*)(ws + 335675392);                       // 131072 B
  unsigned short* WaT = (unsigned short*)(ws + 335806464);      // 131072 B
  unsigned short* WrT = (unsigned short*)(ws + 335937536);      // 262144 B
  unsigned short* mB  = (unsigned short*)(ws + 336199680);      // 262144 B
  float* hbuf         = (float*)(ws + 336461824);               // 262144 B

  dim3 blk(256);
  zero_kernel<<<dim3(256), blk, 0, stream>>>(r1, 65536);
  wconv_kernel<<<dim3(512), blk, 0, stream>>>(Wa, Wr, WaT, WrT);
  transT_kernel<<<dim3(DD / 64, LE / 64, BB), blk, 0, stream>>>(ehr, emask, ehrTm, ehrN, LE, DD);
  transT_kernel<<<dim3(DD / 64, LC / 64, BB), blk, 0, stream>>>(criteria, cmask, critTm, critN, LC, DD);
  proj_mfma<<<dim3(2, (BB * LC) / 128), blk, 0, stream>>>(criteria, WaT, ba, cB);
  proj_mfma<<<dim3(2, (BB * LE) / 128), blk, 0, stream>>>(ehr, WaT, ba, eB);
  attn_fused<<<dim3(1280), dim3(512), 0, stream>>>(cB, eB, ehrTm, critTm, emask, cmask,
                                                   attc, atteP);
  rsum_mfma<<<dim3(2, (BB * LC) / 128), blk, 0, stream>>>(attc, critN, WrT, br, r1, LC);
  rsum_mfma<<<dim3(2, (BB * LE) / 128), blk, 0, stream>>>(atteP, ehrN, WrT, br, r2, LE);
  mbuild_kernel<<<dim3(BB), blk, 0, stream>>>(r1, r2, mB);
  mlp_mfma<<<dim3(MM / 128), blk, 0, stream>>>(mB, Wm, bm, hbuf);
  out3_kernel<<<dim3(BB), blk, 0, stream>>>(hbuf, Wo, bo, out);
}

// Round 3
// 608.635 us; speedup vs baseline: 1.1413x; 1.1413x over previous
//
#include <hip/hip_runtime.h>
#include <hip/hip_bf16.h>

#define BB 128
#define LC 256
#define LE 1024
#define DD 256
#define MM 512

typedef short bf16x8 __attribute__((ext_vector_type(8)));
typedef unsigned short u16x8 __attribute__((ext_vector_type(8)));
typedef unsigned short u16x4 __attribute__((ext_vector_type(4)));
typedef float f32x4 __attribute__((ext_vector_type(4)));

__device__ __forceinline__ unsigned short f2bfu(float f) {
  unsigned int x = __float_as_uint(f);
  return (unsigned short)((x + 0x7fffu + ((x >> 16) & 1u)) >> 16);
}

// ---------------------------------------------------------------------------
// LDS tile layout: linear [r][32 u16] (64B rows) with 16B-chunk XOR swizzle.
// Logical chunk q of row r is STORED at chunk position q ^ ((r>>1)&3).
// b128 frag reads (16 consecutive rows, fixed q): bank starts
// {16*(r&1) + 4*(q^x)} = 8 distinct 16B slots x 2 lanes = 2-way (free, m136).
// global_load_lds writes are linear (base + lane*16) so the SOURCE address
// carries the swizzle (lane at stored pos p fetches logical chunk p^x).
// ---------------------------------------------------------------------------
__device__ __forceinline__ int lx(int r, int q) {
  return r * 32 + (((q ^ ((r >> 1) & 3)) & 3) << 3);
}

__device__ __forceinline__ void gll16(const unsigned short* g, unsigned short* l) {
  __builtin_amdgcn_global_load_lds((const __attribute__((address_space(1))) void*)g,
                                   (__attribute__((address_space(3))) void*)l, 16, 0, 0);
}

// 512-thread: 128x32 tile (4096 u16), one global_load_lds per lane.
__device__ __forceinline__ void stg128(unsigned short* S, const unsigned short* g,
                                       long ldu, int tid) {
  const int l = tid & 63, w = tid >> 6;
  const int r = w * 16 + (l >> 2), q = l & 3;
  gll16(g + (long)r * ldu + (((q ^ ((r >> 1) & 3)) & 3) << 3), S + w * 512);
}

// 512-thread: 256x32 tile (8192 u16), two loads per lane.
__device__ __forceinline__ void stg256(unsigned short* S, const unsigned short* g,
                                       long ldu, int tid) {
  const int l = tid & 63, w = tid >> 6;
#pragma unroll
  for (int it = 0; it < 2; ++it) {
    const int r = it * 128 + w * 16 + (l >> 2), q = l & 3;
    gll16(g + (long)r * ldu + (((q ^ ((r >> 1) & 3)) & 3) << 3), S + it * 4096 + w * 512);
  }
}

// 256-thread: 128x32 tile, two loads per lane (4 waves).
__device__ __forceinline__ void stg128_256(unsigned short* S, const unsigned short* g,
                                           long ldu, int tid) {
  const int l = tid & 63, w = tid >> 6;
#pragma unroll
  for (int it = 0; it < 2; ++it) {
    const int r = it * 64 + w * 16 + (l >> 2), q = l & 3;
    gll16(g + (long)r * ldu + (((q ^ ((r >> 1) & 3)) & 3) << 3), S + it * 2048 + w * 512);
  }
}

// ---- reg-staged f32 -> bf16 into swizzled LDS (256 threads) ----
__device__ __forceinline__ void stage_f32(unsigned short* S, const float* g, long ld, int tid) {
#pragma unroll
  for (int i = 0; i < 2; ++i) {
    int c = tid + i * 256;
    int r = c >> 2, q = c & 3;
    const float4* p = (const float4*)(g + (long)r * ld + q * 8);
    float4 v0 = p[0], v1 = p[1];
    u16x8 o;
    o[0] = f2bfu(v0.x); o[1] = f2bfu(v0.y); o[2] = f2bfu(v0.z); o[3] = f2bfu(v0.w);
    o[4] = f2bfu(v1.x); o[5] = f2bfu(v1.y); o[6] = f2bfu(v1.z); o[7] = f2bfu(v1.w);
    *(u16x8*)&S[lx(r, q)] = o;
  }
}

// ---- 4-wave MFMA step: each wave 64x64 = 4x4 tiles of 16x16x32 ----
__device__ __forceinline__ void mma_step(const unsigned short* As, const unsigned short* Bs,
                                         f32x4 (&acc)[4][4], int wm, int wn, int lane) {
  const int lm = lane & 15, quad = lane >> 4;
  bf16x8 a[4], b[4];
#pragma unroll
  for (int i = 0; i < 4; ++i) {
    a[i] = *(const bf16x8*)&As[lx(wm * 64 + i * 16 + lm, quad)];
    b[i] = *(const bf16x8*)&Bs[lx(wn * 64 + i * 16 + lm, quad)];
  }
#pragma unroll
  for (int i = 0; i < 4; ++i)
#pragma unroll
    for (int j = 0; j < 4; ++j)
      acc[i][j] = __builtin_amdgcn_mfma_f32_16x16x32_bf16(a[i], b[j], acc[i][j], 0, 0, 0);
}

// ---- generic MFMA tile step with independent row offsets ----
template <int MT, int NT>
__device__ __forceinline__ void mma_tiles(const unsigned short* As, const unsigned short* Bs,
                                          f32x4 (&acc)[MT][NT], int m0, int n0, int lane) {
  const int lm = lane & 15, quad = lane >> 4;
  bf16x8 a[MT], b[NT];
#pragma unroll
  for (int i = 0; i < MT; ++i)
    a[i] = *(const bf16x8*)&As[lx(m0 + i * 16 + lm, quad)];
#pragma unroll
  for (int j = 0; j < NT; ++j)
    b[j] = *(const bf16x8*)&Bs[lx(n0 + j * 16 + lm, quad)];
  __builtin_amdgcn_s_setprio(1);
#pragma unroll
  for (int i = 0; i < MT; ++i)
#pragma unroll
    for (int j = 0; j < NT; ++j)
      acc[i][j] = __builtin_amdgcn_mfma_f32_16x16x32_bf16(a[i], b[j], acc[i][j], 0, 0, 0);
  __builtin_amdgcn_s_setprio(0);
}

// ---- zero fill ----
__global__ void zero_kernel(float* __restrict__ p, int n) {
  int i = blockIdx.x * 256 + threadIdx.x;
  if (i < n) p[i] = 0.f;
}

// ---- weight transpose+convert ----
__global__ void wconv_kernel(const float* __restrict__ Wa, const float* __restrict__ Wr,
                             unsigned short* __restrict__ WaT, unsigned short* __restrict__ WrT) {
  int i = blockIdx.x * 256 + threadIdx.x;
  if (i < 65536) WaT[i] = f2bfu(Wa[(i & 255) * 256 + (i >> 8)]);
  if (i < 131072) WrT[i] = f2bfu(Wr[(long)(i & 511) * 256 + (i >> 9)]);
}

// ---- fp32 [R][C] -> (a) mask-baked bf16 transpose dstT[C][R], (b) natural bf16 dstN[R][C]
// T2[64][64] u16 with chunk-XOR (row>>2)&7: write 4-way max, read balanced.
__global__ void transT_kernel(const float* __restrict__ src, const int* __restrict__ mask,
                              unsigned short* __restrict__ dstT, unsigned short* __restrict__ dstN,
                              int R, int C) {
  __shared__ unsigned short T2[64 * 64];
  const int tid = threadIdx.x, b = blockIdx.z;
  const int r0 = blockIdx.y * 64, c0 = blockIdx.x * 64;
  const float* s = src + (long)b * R * C;
  const int* mk = mask + (long)b * R;
  unsigned short* dT = dstT + (long)b * R * C;
  unsigned short* dN = dstN + (long)b * R * C;
#pragma unroll
  for (int i = 0; i < 4; ++i) {
    int r = (tid >> 4) + i * 16, c4 = tid & 15;
    float4 v = *(const float4*)(s + (long)(r0 + r) * C + c0 + c4 * 4);
    u16x4 nat;
    nat[0] = f2bfu(v.x); nat[1] = f2bfu(v.y); nat[2] = f2bfu(v.z); nat[3] = f2bfu(v.w);
    *(u16x4*)(dN + (long)(r0 + r) * C + c0 + c4 * 4) = nat;
    float g = mk[r0 + r] ? 1.f : 0.f;
    float vm[4] = {v.x * g, v.y * g, v.z * g, v.w * g};
#pragma unroll
    for (int k = 0; k < 4; ++k) {
      int row = c4 * 4 + k;  // transposed row = original col
      T2[row * 64 + (((r >> 3) ^ (row >> 2)) & 7) * 8 + (r & 7)] = f2bfu(vm[k]);
    }
  }
  __syncthreads();
#pragma unroll
  for (int j = 0; j < 2; ++j) {
    int idx = tid * 2 + j;
    int row = idx >> 3, ch = idx & 7;
    *(u16x8*)(dT + (long)(c0 + row) * R + r0 + ch * 8) =
        *(const u16x8*)&T2[row * 64 + ((ch ^ (row >> 2)) & 7) * 8];
  }
}

// ---- proj: out = relu(A @ Wa + ba) -> bf16. A f32 reg-staged, B gll, dbuf. ----
__global__ __launch_bounds__(256, 2) void proj_mfma(const float* __restrict__ A,
                                                    const unsigned short* __restrict__ WaT,
                                                    const float* __restrict__ ba,
                                                    unsigned short* __restrict__ out) {
  __shared__ unsigned short As[2][4096], Bs[2][4096];
  const int tid = threadIdx.x, lane = tid & 63, w = tid >> 6, wm = w >> 1, wn = w & 1;
  const long m0 = (long)blockIdx.y * 128;
  const int n0 = blockIdx.x * 128;
  f32x4 acc[4][4] = {};
  stage_f32(As[0], A + m0 * DD, DD, tid);
  stg128_256(Bs[0], WaT + (long)n0 * DD, DD, tid);
  __syncthreads();
  for (int s = 0; s < 8; ++s) {
    if (s < 7) {
      stage_f32(As[(s + 1) & 1], A + m0 * DD + (s + 1) * 32, DD, tid);
      stg128_256(Bs[(s + 1) & 1], WaT + (long)n0 * DD + (s + 1) * 32, DD, tid);
    }
    mma_step(As[s & 1], Bs[s & 1], acc, wm, wn, lane);
    __syncthreads();
  }
  const int lm = lane & 15, quad = lane >> 4;
#pragma unroll
  for (int i = 0; i < 4; ++i)
#pragma unroll
    for (int j = 0; j < 4; ++j) {
      int col = n0 + wn * 64 + j * 16 + lm;
      float bias = ba[col];
#pragma unroll
      for (int r = 0; r < 4; ++r) {
        long row = m0 + wm * 64 + i * 16 + quad * 4 + r;
        float v = acc[i][j][r] + bias;
        out[row * DD + col] = f2bfu(v > 0.f ? v : 0.f);
      }
    }
}

// ============================================================================
// Fused attention body (one direction). Per 128-row output tile:
//  loop ch: S^T = aSrc_chunk @ resB^T (MFMA), exp -> S4 (LDS), masked denom,
//           acc += S4 @ pvB_chunk^T. All staging via global_load_lds + dbuf,
//           single barrier per k-step; PV chunk0 prefetched under S-phase
//           tail, next-ch S chunk prefetched under PV tail.
// LDS: STG 2 slots x (A 4096 | B 4096) u16; PV slot = contiguous 8192.
//      S4 = 4 x 4096 u16 (exp'd scores). Total 64.5 KB -> 2 blocks/CU.
// ============================================================================
__device__ __forceinline__ void attn_body(
    unsigned short* STG, unsigned short* S4, float* asum_s,
    const unsigned short* resB, const unsigned short* aSrc,
    const unsigned short* pvB, long pvLd, int nch,
    const int* mask, unsigned short* outp, int tid) {
  const int lane = tid & 63, w = tid >> 6;
  const int lm = lane & 15, quad = lane >> 4;
  const int wmS = w >> 2, wnS = w & 3;  // S: contraction 64-half, out-row 32-quarter
  const int wm = w >> 2, wn = w & 3;    // PV: out-row 64-half, D 64-quarter
  f32x4 acc[4][4] = {};
  float ap0 = 0.f, ap1 = 0.f;
  stg128(STG, aSrc, DD, tid);
  stg128(STG + 4096, resB, DD, tid);
  __syncthreads();
  for (int ch = 0; ch < nch; ++ch) {
    const unsigned short* Ag = aSrc + (long)ch * 128 * DD;
    f32x4 accS[4][2] = {};
    for (int s = 0; s < 8; ++s) {
      if (s < 7) {
        unsigned short* d = STG + ((s + 1) & 1) * 8192;
        stg128(d, Ag + (s + 1) * 32, DD, tid);
        stg128(d + 4096, resB + (s + 1) * 32, DD, tid);
      } else {
        stg256(STG, pvB + (long)ch * 128, pvLd, tid);  // PV chunk0 -> slot 0
      }
      const unsigned short* base = STG + (s & 1) * 8192;
      mma_tiles<4, 2>(base, base + 4096, accS, wmS * 64, wnS * 32, lane);
      __syncthreads();
    }
    // exp + pack into S4 + masked denominator partials
#pragma unroll
    for (int i = 0; i < 4; ++i) {
      const int A0 = wmS * 64 + i * 16 + quad * 4;
      const int4 m4 = *(const int4*)(mask + ch * 128 + A0);
      const float g0 = m4.x ? 1.f : 0.f, g1 = m4.y ? 1.f : 0.f;
      const float g2 = m4.z ? 1.f : 0.f, g3 = m4.w ? 1.f : 0.f;
      const int kk = A0 >> 5, wi = A0 & 31;
      const int qq = wi >> 3, sub = wi & 7;  // sub in {0,4}: 8B aligned
#pragma unroll
      for (int j = 0; j < 2; ++j) {
        const int row = wnS * 32 + j * 16 + lm;
        float e0 = __expf(accS[i][j][0]);
        float e1 = __expf(accS[i][j][1]);
        float e2 = __expf(accS[i][j][2]);
        float e3 = __expf(accS[i][j][3]);
        float sm = g0 * e0 + g1 * e1 + g2 * e2 + g3 * e3;
        if (j == 0) ap0 += sm; else ap1 += sm;
        u16x4 pk;
        pk[0] = f2bfu(e0); pk[1] = f2bfu(e1); pk[2] = f2bfu(e2); pk[3] = f2bfu(e3);
        *(u16x4*)&S4[kk * 4096 + row * 32 + ((qq ^ ((row >> 1) & 3)) << 3) + sub] = pk;
      }
    }
    __syncthreads();
    for (int kk = 0; kk < 4; ++kk) {
      if (kk < 3) {
        stg256(STG + ((kk + 1) & 1) * 8192, pvB + (long)ch * 128 + (kk + 1) * 32, pvLd, tid);
      } else if (ch + 1 < nch) {
        stg128(STG, aSrc + (long)(ch + 1) * 128 * DD, DD, tid);
        stg128(STG + 4096, resB, DD, tid);
      }
      mma_tiles<4, 4>(S4 + kk * 4096, STG + (kk & 1) * 8192, acc, wm * 64, wn * 64, lane);
      __syncthreads();
    }
  }
  if (tid < 128) asum_s[tid] = 0.f;
  __syncthreads();
  {
    float s = ap0;
    s += __shfl_xor(s, 16); s += __shfl_xor(s, 32);
    if (quad == 0) atomicAdd(&asum_s[wnS * 32 + lm], s);
    float t = ap1;
    t += __shfl_xor(t, 16); t += __shfl_xor(t, 32);
    if (quad == 0) atomicAdd(&asum_s[wnS * 32 + 16 + lm], t);
  }
  __syncthreads();
  float rs[4][4];
#pragma unroll
  for (int i = 0; i < 4; ++i)
#pragma unroll
    for (int r = 0; r < 4; ++r)
      rs[i][r] = 1.f / asum_s[wm * 64 + i * 16 + quad * 4 + r];
#pragma unroll
  for (int i = 0; i < 4; ++i)
#pragma unroll
    for (int j = 0; j < 4; ++j) {
      int col = wn * 64 + j * 16 + lm;
#pragma unroll
      for (int r = 0; r < 4; ++r) {
        int row = wm * 64 + i * 16 + quad * 4 + r;
        outp[(long)row * DD + col] = f2bfu(acc[i][j][r] * rs[i][r]);
      }
    }
}

__global__ __launch_bounds__(512, 2) void attn_c_fused(
    const unsigned short* __restrict__ cB, const unsigned short* __restrict__ eB,
    const unsigned short* __restrict__ ehrTm, const int* __restrict__ em,
    unsigned short* __restrict__ attc) {
  __shared__ unsigned short STG[16384];
  __shared__ unsigned short S4[16384];
  __shared__ float asum_s[128];
  const int tid = threadIdx.x, fid = blockIdx.x;
  const int lid = (fid & 7) * 32 + (fid >> 3);  // b-pairs share an XCD L2
  const int b = lid >> 1, m0 = (lid & 1) * 128;
  attn_body(STG, S4, asum_s, cB + ((long)b * LC + m0) * DD, eB + (long)b * LE * DD,
            ehrTm + (long)b * DD * LE, LE, 8, em + (long)b * LE,
            attc + ((long)b * LC + m0) * DD, tid);
}

__global__ __launch_bounds__(512, 2) void attn_e_fused(
    const unsigned short* __restrict__ cB, const unsigned short* __restrict__ eB,
    const unsigned short* __restrict__ critTm, const int* __restrict__ cm,
    unsigned short* __restrict__ atte) {
  __shared__ unsigned short STG[16384];
  __shared__ unsigned short S4[16384];
  __shared__ float asum_s[128];
  const int tid = threadIdx.x, fid = blockIdx.x;
  const int lid = (fid & 7) * 128 + (fid >> 3);  // same b->XCD mapping as c-side
  const int b = lid >> 3, n0 = (lid & 7) * 128;
  attn_body(STG, S4, asum_s, eB + ((long)b * LE + n0) * DD, cB + (long)b * LC * DD,
            critTm + (long)b * DD * LC, LC, 2, cm + (long)b * LC,
            atte + ((long)b * LE + n0) * DD, tid);
}

// ---- r = sum_seq relu([att | origB] @ Wr + br), all gll staging, dbuf ----
__global__ __launch_bounds__(256, 2) void rsum_mfma(const unsigned short* __restrict__ att,
                                                    const unsigned short* __restrict__ origB,
                                                    const unsigned short* __restrict__ WrT,
                                                    const float* __restrict__ br,
                                                    float* __restrict__ rout, int Lseq) {
  __shared__ unsigned short As[2][4096], Bs[2][4096];
  __shared__ float red[2][128];
  const int tid = threadIdx.x, lane = tid & 63, w = tid >> 6, wm = w >> 1, wn = w & 1;
  const long m0 = (long)blockIdx.y * 128;
  const int n0 = blockIdx.x * 128;
  const int b = (int)(m0 / Lseq);
  f32x4 acc[4][4] = {};
  stg128_256(As[0], att + m0 * DD, DD, tid);
  stg128_256(Bs[0], WrT + (long)n0 * 512, 512, tid);
  __syncthreads();
  for (int s = 0; s < 16; ++s) {
    if (s < 15) {
      const int k1 = (s + 1) * 32;
      const unsigned short* aSrc =
          (k1 < DD) ? att + m0 * DD + k1 : origB + m0 * DD + (k1 - DD);
      stg128_256(As[(s + 1) & 1], aSrc, DD, tid);
      stg128_256(Bs[(s + 1) & 1], WrT + (long)n0 * 512 + k1, 512, tid);
    }
    mma_step(As[s & 1], Bs[s & 1], acc, wm, wn, lane);
    __syncthreads();
  }
  const int lm = lane & 15, quad = lane >> 4;
#pragma unroll
  for (int j = 0; j < 4; ++j) {
    int col = n0 + wn * 64 + j * 16 + lm;
    float bias = br[col];
    float s = 0.f;
#pragma unroll
    for (int i = 0; i < 4; ++i)
#pragma unroll
      for (int r = 0; r < 4; ++r) {
        float v = acc[i][j][r] + bias;
        s += v > 0.f ? v : 0.f;
      }
    s += __shfl_xor(s, 16);
    s += __shfl_xor(s, 32);
    if (quad == 0) red[wm][wn * 64 + j * 16 + lm] = s;
  }
  __syncthreads();
  if (tid < 128)
    atomicAdd(&rout[b * DD + n0 + tid], red[0][tid] + red[1][tid]);
}

// ---- build m = [r1 | r2 | r1*r2 | r1-r2] as bf16 [128][1024] ----
__global__ void mbuild_kernel(const float* __restrict__ r1, const float* __restrict__ r2,
                              unsigned short* __restrict__ mB) {
  int i = blockIdx.x * 256 + threadIdx.x;
  int b = i >> 8, d = i & 255;
  float v1 = r1[i], v2 = r2[i];
  unsigned short* row = mB + (long)b * 1024;
  row[d] = f2bfu(v1);
  row[256 + d] = f2bfu(v2);
  row[512 + d] = f2bfu(v1 * v2);
  row[768 + d] = f2bfu(v1 - v2);
}

// ---- h = relu(m @ Wm + bm): M=128, N=512, K=1024 MFMA GEMM ----
__global__ __launch_bounds__(256, 2) void mlp_mfma(const unsigned short* __restrict__ mB,
                                                   const float* __restrict__ Wm,
                                                   const float* __restrict__ bm,
                                                   float* __restrict__ h) {
  __shared__ unsigned short As[4096], Bs[4096];
  const int tid = threadIdx.x, lane = tid & 63, w = tid >> 6, wm = w >> 1, wn = w & 1;
  const int n0 = blockIdx.x * 128;
  f32x4 acc[4][4] = {};
  for (int k0 = 0; k0 < 4 * DD; k0 += 32) {
    stg128_256(As, mB + k0, 1024, tid);
    {
      const int dcc = tid & 7, er = tid >> 3;
#pragma unroll
      for (int i = 0; i < 4; ++i) {
        int nch = dcc + i * 8;
        float4 v = *(const float4*)(Wm + (long)(k0 + er) * MM + n0 + nch * 4);
        float vv[4] = {v.x, v.y, v.z, v.w};
#pragma unroll
        for (int q = 0; q < 4; ++q)
          Bs[lx(nch * 4 + q, er >> 3) + (er & 7)] = f2bfu(vv[q]);
      }
    }
    __syncthreads();
    mma_step(As, Bs, acc, wm, wn, lane);
    __syncthreads();
  }
  const int lm = lane & 15, quad = lane >> 4;
#pragma unroll
  for (int i = 0; i < 4; ++i)
#pragma unroll
    for (int j = 0; j < 4; ++j) {
      int col = n0 + wn * 64 + j * 16 + lm;
      float bias = bm[col];
#pragma unroll
      for (int r = 0; r < 4; ++r) {
        int row = wm * 64 + i * 16 + quad * 4 + r;
        float v = acc[i][j][r] + bias;
        h[(long)row * MM + col] = v > 0.f ? v : 0.f;
      }
    }
}

// ---- out = h @ Wo + bo ----
__global__ void out3_kernel(const float* __restrict__ h, const float* __restrict__ Wo,
                            const float* __restrict__ bo, float* __restrict__ out) {
  const int b = blockIdx.x, tid = threadIdx.x;
  __shared__ float red[256];
  float a[3] = {0.f, 0.f, 0.f};
  for (int k = tid; k < MM; k += 256) {
    float hv = h[(long)b * MM + k];
    a[0] += hv * Wo[k * 3 + 0];
    a[1] += hv * Wo[k * 3 + 1];
    a[2] += hv * Wo[k * 3 + 2];
  }
#pragma unroll
  for (int o = 0; o < 3; ++o) {
    red[tid] = a[o]; __syncthreads();
    for (int st = 128; st > 0; st >>= 1) {
      if (tid < st) red[tid] += red[tid + st];
      __syncthreads();
    }
    if (tid == 0) out[b * 3 + o] = red[0] + bo[o];
    __syncthreads();
  }
}

extern "C" void kernel_launch(void* const* d_in, const int* in_sizes, int n_in,
                              void* d_out, int out_size, void* d_ws, size_t ws_size,
                              hipStream_t stream) {
  const float* criteria = (const float*)d_in[0];
  const float* ehr      = (const float*)d_in[1];
  const int*   cmask    = (const int*)d_in[2];
  const int*   emask    = (const int*)d_in[3];
  const float* Wa       = (const float*)d_in[4];
  const float* ba       = (const float*)d_in[5];
  const float* Wr       = (const float*)d_in[6];
  const float* br       = (const float*)d_in[7];
  const float* Wm       = (const float*)d_in[8];
  const float* bm       = (const float*)d_in[9];
  const float* Wo       = (const float*)d_in[10];
  const float* bo       = (const float*)d_in[11];
  float* out = (float*)d_out;

  char* ws = (char*)d_ws;
  unsigned short* cB     = (unsigned short*)(ws);               // 16.78 MB
  unsigned short* eB     = (unsigned short*)(ws + 16777216);    // 67.1 MB
  unsigned short* ehrTm  = (unsigned short*)(ws + 83886080);    // 67.1 MB, em-masked ehr^T
  unsigned short* critTm = (unsigned short*)(ws + 150994944);   // 16.78 MB, cm-masked crit^T
  unsigned short* ehrN   = (unsigned short*)(ws + 167772160);   // 67.1 MB natural bf16 ehr
  unsigned short* critN  = (unsigned short*)(ws + 234881024);   // 16.78 MB natural bf16 crit
  unsigned short* attc   = (unsigned short*)(ws + 251658240);   // 16.78 MB
  unsigned short* atteP  = (unsigned short*)(ws + 268435456);   // 67.1 MB
  float* r1   = (float*)(ws + 335544320);                       // 131072 B
  float* r2   = (float*)(ws + 335675392);                       // 131072 B
  unsigned short* WaT = (unsigned short*)(ws + 335806464);      // 131072 B
  unsigned short* WrT = (unsigned short*)(ws + 335937536);      // 262144 B
  unsigned short* mB  = (unsigned short*)(ws + 336199680);      // 262144 B
  float* hbuf         = (float*)(ws + 336461824);               // 262144 B

  dim3 blk(256);
  zero_kernel<<<dim3(256), blk, 0, stream>>>(r1, 65536);
  wconv_kernel<<<dim3(512), blk, 0, stream>>>(Wa, Wr, WaT, WrT);
  transT_kernel<<<dim3(DD / 64, LE / 64, BB), blk, 0, stream>>>(ehr, emask, ehrTm, ehrN, LE, DD);
  transT_kernel<<<dim3(DD / 64, LC / 64, BB), blk, 0, stream>>>(criteria, cmask, critTm, critN, LC, DD);
  proj_mfma<<<dim3(2, (BB * LC) / 128), blk, 0, stream>>>(criteria, WaT, ba, cB);
  proj_mfma<<<dim3(2, (BB * LE) / 128), blk, 0, stream>>>(ehr, WaT, ba, eB);
  attn_c_fused<<<dim3(256), dim3(512), 0, stream>>>(cB, eB, ehrTm, emask, attc);
  attn_e_fused<<<dim3(1024), dim3(512), 0, stream>>>(cB, eB, critTm, cmask, atteP);
  rsum_mfma<<<dim3(2, (BB * LC) / 128), blk, 0, stream>>>(attc, critN, WrT, br, r1, LC);
  rsum_mfma<<<dim3(2, (BB * LE) / 128), blk, 0, stream>>>(atteP, ehrN, WrT, br, r2, LE);
  mbuild_kernel<<<dim3(BB), blk, 0, stream>>>(r1, r2, mB);
  mlp_mfma<<<dim3(MM / 128), blk, 0, stream>>>(mB, Wm, bm, hbuf);
  out3_kernel<<<dim3(BB), blk, 0, stream>>>(hbuf, Wo, bo, out);
}

// Round 4
// 588.617 us; speedup vs baseline: 1.1802x; 1.0340x over previous
//
#include <hip/hip_runtime.h>
#include <hip/hip_bf16.h>

#define BB 128
#define LC 256
#define LE 1024
#define DD 256
#define MM 512

typedef short bf16x8 __attribute__((ext_vector_type(8)));
typedef unsigned short u16x8 __attribute__((ext_vector_type(8)));
typedef unsigned short u16x4 __attribute__((ext_vector_type(4)));
typedef float f32x4 __attribute__((ext_vector_type(4)));

__device__ __forceinline__ unsigned short f2bfu(float f) {
  unsigned int x = __float_as_uint(f);
  return (unsigned short)((x + 0x7fffu + ((x >> 16) & 1u)) >> 16);
}

// ---------------------------------------------------------------------------
// LDS tile layout: linear [r][32 u16] (64B rows) with 16B-chunk XOR swizzle.
// Logical chunk q of row r is STORED at chunk position q ^ ((r>>1)&3).
// b128 frag reads (16 consecutive rows, fixed q): 8 distinct 16B slots x 2
// lanes = 2-way (free, m136). global_load_lds writes are linear so the
// SOURCE address carries the swizzle.
// ---------------------------------------------------------------------------
__device__ __forceinline__ int lx(int r, int q) {
  return r * 32 + (((q ^ ((r >> 1) & 3)) & 3) << 3);
}

__device__ __forceinline__ void gll16(const unsigned short* g, unsigned short* l) {
  __builtin_amdgcn_global_load_lds((const __attribute__((address_space(1))) void*)g,
                                   (__attribute__((address_space(3))) void*)l, 16, 0, 0);
}

// 512-thread: 128x32 tile (4096 u16), one global_load_lds per lane.
__device__ __forceinline__ void stg128(unsigned short* S, const unsigned short* g,
                                       long ldu, int tid) {
  const int l = tid & 63, w = tid >> 6;
  const int r = w * 16 + (l >> 2), q = l & 3;
  gll16(g + (long)r * ldu + (((q ^ ((r >> 1) & 3)) & 3) << 3), S + w * 512);
}

// 512-thread: 256x32 tile (8192 u16), two loads per lane.
__device__ __forceinline__ void stg256(unsigned short* S, const unsigned short* g,
                                       long ldu, int tid) {
  const int l = tid & 63, w = tid >> 6;
#pragma unroll
  for (int it = 0; it < 2; ++it) {
    const int r = it * 128 + w * 16 + (l >> 2), q = l & 3;
    gll16(g + (long)r * ldu + (((q ^ ((r >> 1) & 3)) & 3) << 3), S + it * 4096 + w * 512);
  }
}

// 256-thread: 128x32 tile, two loads per lane (4 waves).
__device__ __forceinline__ void stg128_256(unsigned short* S, const unsigned short* g,
                                           long ldu, int tid) {
  const int l = tid & 63, w = tid >> 6;
#pragma unroll
  for (int it = 0; it < 2; ++it) {
    const int r = it * 64 + w * 16 + (l >> 2), q = l & 3;
    gll16(g + (long)r * ldu + (((q ^ ((r >> 1) & 3)) & 3) << 3), S + it * 2048 + w * 512);
  }
}

// ---- reg-staged f32 -> bf16 into swizzled LDS (256 threads) ----
__device__ __forceinline__ void stage_f32(unsigned short* S, const float* g, long ld, int tid) {
#pragma unroll
  for (int i = 0; i < 2; ++i) {
    int c = tid + i * 256;
    int r = c >> 2, q = c & 3;
    const float4* p = (const float4*)(g + (long)r * ld + q * 8);
    float4 v0 = p[0], v1 = p[1];
    u16x8 o;
    o[0] = f2bfu(v0.x); o[1] = f2bfu(v0.y); o[2] = f2bfu(v0.z); o[3] = f2bfu(v0.w);
    o[4] = f2bfu(v1.x); o[5] = f2bfu(v1.y); o[6] = f2bfu(v1.z); o[7] = f2bfu(v1.w);
    *(u16x8*)&S[lx(r, q)] = o;
  }
}

// ---- 4-wave MFMA step: each wave 64x64 = 4x4 tiles of 16x16x32 ----
__device__ __forceinline__ void mma_step(const unsigned short* As, const unsigned short* Bs,
                                         f32x4 (&acc)[4][4], int wm, int wn, int lane) {
  const int lm = lane & 15, quad = lane >> 4;
  bf16x8 a[4], b[4];
#pragma unroll
  for (int i = 0; i < 4; ++i) {
    a[i] = *(const bf16x8*)&As[lx(wm * 64 + i * 16 + lm, quad)];
    b[i] = *(const bf16x8*)&Bs[lx(wn * 64 + i * 16 + lm, quad)];
  }
  __builtin_amdgcn_s_setprio(1);
#pragma unroll
  for (int i = 0; i < 4; ++i)
#pragma unroll
    for (int j = 0; j < 4; ++j)
      acc[i][j] = __builtin_amdgcn_mfma_f32_16x16x32_bf16(a[i], b[j], acc[i][j], 0, 0, 0);
  __builtin_amdgcn_s_setprio(0);
}

// ---- generic MFMA tile step with independent row offsets ----
template <int MT, int NT>
__device__ __forceinline__ void mma_tiles(const unsigned short* As, const unsigned short* Bs,
                                          f32x4 (&acc)[MT][NT], int m0, int n0, int lane) {
  const int lm = lane & 15, quad = lane >> 4;
  bf16x8 a[MT], b[NT];
#pragma unroll
  for (int i = 0; i < MT; ++i)
    a[i] = *(const bf16x8*)&As[lx(m0 + i * 16 + lm, quad)];
#pragma unroll
  for (int j = 0; j < NT; ++j)
    b[j] = *(const bf16x8*)&Bs[lx(n0 + j * 16 + lm, quad)];
  __builtin_amdgcn_s_setprio(1);
#pragma unroll
  for (int i = 0; i < MT; ++i)
#pragma unroll
    for (int j = 0; j < NT; ++j)
      acc[i][j] = __builtin_amdgcn_mfma_f32_16x16x32_bf16(a[i], b[j], acc[i][j], 0, 0, 0);
  __builtin_amdgcn_s_setprio(0);
}

// ---- zero fill ----
__global__ void zero_kernel(float* __restrict__ p, int n) {
  int i = blockIdx.x * 256 + threadIdx.x;
  if (i < n) p[i] = 0.f;
}

// ---- weight transpose+convert ----
__global__ void wconv_kernel(const float* __restrict__ Wa, const float* __restrict__ Wr,
                             unsigned short* __restrict__ WaT, unsigned short* __restrict__ WrT) {
  int i = blockIdx.x * 256 + threadIdx.x;
  if (i < 65536) WaT[i] = f2bfu(Wa[(i & 255) * 256 + (i >> 8)]);
  if (i < 131072) WrT[i] = f2bfu(Wr[(long)(i & 511) * 256 + (i >> 9)]);
}

// ---- fp32 [R][C] -> (a) mask-baked bf16 transpose dstT[C][R], (b) natural bf16 dstN[R][C]
__global__ void transT_kernel(const float* __restrict__ src, const int* __restrict__ mask,
                              unsigned short* __restrict__ dstT, unsigned short* __restrict__ dstN,
                              int R, int C) {
  __shared__ unsigned short T2[64 * 64];
  const int tid = threadIdx.x, b = blockIdx.z;
  const int r0 = blockIdx.y * 64, c0 = blockIdx.x * 64;
  const float* s = src + (long)b * R * C;
  const int* mk = mask + (long)b * R;
  unsigned short* dT = dstT + (long)b * R * C;
  unsigned short* dN = dstN + (long)b * R * C;
#pragma unroll
  for (int i = 0; i < 4; ++i) {
    int r = (tid >> 4) + i * 16, c4 = tid & 15;
    float4 v = *(const float4*)(s + (long)(r0 + r) * C + c0 + c4 * 4);
    u16x4 nat;
    nat[0] = f2bfu(v.x); nat[1] = f2bfu(v.y); nat[2] = f2bfu(v.z); nat[3] = f2bfu(v.w);
    *(u16x4*)(dN + (long)(r0 + r) * C + c0 + c4 * 4) = nat;
    float g = mk[r0 + r] ? 1.f : 0.f;
    float vm[4] = {v.x * g, v.y * g, v.z * g, v.w * g};
#pragma unroll
    for (int k = 0; k < 4; ++k) {
      int row = c4 * 4 + k;
      T2[row * 64 + (((r >> 3) ^ (row >> 2)) & 7) * 8 + (r & 7)] = f2bfu(vm[k]);
    }
  }
  __syncthreads();
#pragma unroll
  for (int j = 0; j < 2; ++j) {
    int idx = tid * 2 + j;
    int row = idx >> 3, ch = idx & 7;
    *(u16x8*)(dT + (long)(c0 + row) * R + r0 + ch * 8) =
        *(const u16x8*)&T2[row * 64 + ((ch ^ (row >> 2)) & 7) * 8];
  }
}

// ---- proj: out = relu(A @ Wa + ba) -> bf16. A f32 reg-staged, B gll, dbuf. ----
__global__ __launch_bounds__(256, 2) void proj_mfma(const float* __restrict__ A,
                                                    const unsigned short* __restrict__ WaT,
                                                    const float* __restrict__ ba,
                                                    unsigned short* __restrict__ out) {
  __shared__ unsigned short As[2][4096], Bs[2][4096];
  const int tid = threadIdx.x, lane = tid & 63, w = tid >> 6, wm = w >> 1, wn = w & 1;
  const long m0 = (long)blockIdx.y * 128;
  const int n0 = blockIdx.x * 128;
  f32x4 acc[4][4] = {};
  stage_f32(As[0], A + m0 * DD, DD, tid);
  stg128_256(Bs[0], WaT + (long)n0 * DD, DD, tid);
  __syncthreads();
  for (int s = 0; s < 8; ++s) {
    if (s < 7) {
      stage_f32(As[(s + 1) & 1], A + m0 * DD + (s + 1) * 32, DD, tid);
      stg128_256(Bs[(s + 1) & 1], WaT + (long)n0 * DD + (s + 1) * 32, DD, tid);
    }
    mma_step(As[s & 1], Bs[s & 1], acc, wm, wn, lane);
    __syncthreads();
  }
  const int lm = lane & 15, quad = lane >> 4;
#pragma unroll
  for (int i = 0; i < 4; ++i)
#pragma unroll
    for (int j = 0; j < 4; ++j) {
      int col = n0 + wn * 64 + j * 16 + lm;
      float bias = ba[col];
#pragma unroll
      for (int r = 0; r < 4; ++r) {
        long row = m0 + wm * 64 + i * 16 + quad * 4 + r;
        float v = acc[i][j][r] + bias;
        out[row * DD + col] = f2bfu(v > 0.f ? v : 0.f);
      }
    }
}

// ============================================================================
// Fused attention body. Step stream: per chunk, 8 S-steps + 4 PV-steps =
// 12 steps (12 % 3 == 0 -> slot indices constant-fold). Every step stages
// exactly 2 global_load_lds per thread. 3 rotating 16KB slots, 2-deep
// prefetch, counted s_waitcnt vmcnt(2) + raw s_barrier (loads for step t+1
// and t+2 stay in flight across the barrier). Slot-rotation safety: write
// to (t+2)%3 == (t-1)%3 is issued after barrier t; the lgkmcnt(0) before
// barrier t guarantees every wave's iter t-1 ds_reads completed.
// LDS: 3*16KB slots + 32KB S4 = 81920 B exactly -> 2 blocks/CU.
// asum aliases slot 0 (only used after the staging stream drains).
// ============================================================================
template <int NCH>
__device__ __forceinline__ void attn_body(
    unsigned short* SLOT, unsigned short* S4,
    const unsigned short* resB, const unsigned short* aSrc,
    const unsigned short* pvB, long pvLd,
    const int* mask, unsigned short* outp, int tid) {
  const int lane = tid & 63, w = tid >> 6;
  const int lm = lane & 15, quad = lane >> 4;
  const int wmS = w >> 2, wnS = w & 3;  // S: contraction 64-half, out-row 32-quarter
  const int wm = w >> 2, wn = w & 3;    // PV: out-row 64-half, D 64-quarter
  float* asum_s = (float*)SLOT;
  f32x4 acc[4][4] = {};
  float ap0 = 0.f, ap1 = 0.f;
  // prologue: steps 0,1 (S s=0,1) -> slots 0,1 (4 loads outstanding)
  stg128(SLOT, aSrc, DD, tid);
  stg128(SLOT + 4096, resB, DD, tid);
  stg128(SLOT + 8192, aSrc + 32, DD, tid);
  stg128(SLOT + 8192 + 4096, resB + 32, DD, tid);
  for (int ch = 0; ch < NCH; ++ch) {
    const unsigned short* Ag = aSrc + (long)ch * 128 * DD;
    const unsigned short* Pg = pvB + (long)ch * 128;
    f32x4 accS[4][2] = {};
#pragma unroll
    for (int s = 0; s < 8; ++s) {
      asm volatile("s_waitcnt vmcnt(2) lgkmcnt(0)" ::: "memory");
      __builtin_amdgcn_s_barrier();
      if (s < 6) {
        unsigned short* d = SLOT + ((s + 2) % 3) * 8192;
        stg128(d, Ag + (s + 2) * 32, DD, tid);
        stg128(d + 4096, resB + (s + 2) * 32, DD, tid);
      } else if (s == 6) {
        stg256(SLOT + 2 * 8192, Pg, pvLd, tid);        // PV kk=0 -> slot 2
      } else {
        stg256(SLOT, Pg + 32, pvLd, tid);              // PV kk=1 -> slot 0
      }
      const unsigned short* base = SLOT + (s % 3) * 8192;
      mma_tiles<4, 2>(base, base + 4096, accS, wmS * 64, wnS * 32, lane);
    }
    // ---- exp + pack into S4 + masked denominator partials ----
#pragma unroll
    for (int i = 0; i < 4; ++i) {
      const int A0 = wmS * 64 + i * 16 + quad * 4;
      const int4 m4 = *(const int4*)(mask + ch * 128 + A0);
      const float g0 = m4.x ? 1.f : 0.f, g1 = m4.y ? 1.f : 0.f;
      const float g2 = m4.z ? 1.f : 0.f, g3 = m4.w ? 1.f : 0.f;
      const int kk = A0 >> 5, wi = A0 & 31;
      const int qq = wi >> 3, sub = wi & 7;
#pragma unroll
      for (int j = 0; j < 2; ++j) {
        const int row = wnS * 32 + j * 16 + lm;
        float e0 = __expf(accS[i][j][0]);
        float e1 = __expf(accS[i][j][1]);
        float e2 = __expf(accS[i][j][2]);
        float e3 = __expf(accS[i][j][3]);
        float sm = g0 * e0 + g1 * e1 + g2 * e2 + g3 * e3;
        if (j == 0) ap0 += sm; else ap1 += sm;
        u16x4 pk;
        pk[0] = f2bfu(e0); pk[1] = f2bfu(e1); pk[2] = f2bfu(e2); pk[3] = f2bfu(e3);
        *(u16x4*)&S4[kk * 4096 + row * 32 + ((qq ^ ((row >> 1) & 3)) << 3) + sub] = pk;
      }
    }
#pragma unroll
    for (int kk = 0; kk < 4; ++kk) {
      if ((kk == 3) && (ch == NCH - 1))
        asm volatile("s_waitcnt vmcnt(0) lgkmcnt(0)" ::: "memory");
      else
        asm volatile("s_waitcnt vmcnt(2) lgkmcnt(0)" ::: "memory");
      __builtin_amdgcn_s_barrier();
      if (kk < 2) {
        stg256(SLOT + ((kk + 1) % 3) * 8192, Pg + (kk + 2) * 32, pvLd, tid);
      } else if (ch + 1 < NCH) {
        unsigned short* d = SLOT + (kk - 2) * 8192;    // kk=2 -> slot0, kk=3 -> slot1
        stg128(d, aSrc + (long)(ch + 1) * 128 * DD + (kk - 2) * 32, DD, tid);
        stg128(d + 4096, resB + (kk - 2) * 32, DD, tid);
      }
      mma_tiles<4, 4>(S4 + kk * 4096, SLOT + ((kk + 2) % 3) * 8192, acc,
                      wm * 64, wn * 64, lane);
    }
  }
  // ---- block-local softmax denominators ----
  if (tid < 128) asum_s[tid] = 0.f;
  __syncthreads();
  {
    float s = ap0;
    s += __shfl_xor(s, 16); s += __shfl_xor(s, 32);
    if (quad == 0) atomicAdd(&asum_s[wnS * 32 + lm], s);
    float t = ap1;
    t += __shfl_xor(t, 16); t += __shfl_xor(t, 32);
    if (quad == 0) atomicAdd(&asum_s[wnS * 32 + 16 + lm], t);
  }
  __syncthreads();
  float rs[4][4];
#pragma unroll
  for (int i = 0; i < 4; ++i)
#pragma unroll
    for (int r = 0; r < 4; ++r)
      rs[i][r] = 1.f / asum_s[wm * 64 + i * 16 + quad * 4 + r];
#pragma unroll
  for (int i = 0; i < 4; ++i)
#pragma unroll
    for (int j = 0; j < 4; ++j) {
      int col = wn * 64 + j * 16 + lm;
#pragma unroll
      for (int r = 0; r < 4; ++r) {
        int row = wm * 64 + i * 16 + quad * 4 + r;
        outp[(long)row * DD + col] = f2bfu(acc[i][j][r] * rs[i][r]);
      }
    }
}

__global__ __launch_bounds__(512, 2) void attn_c_fused(
    const unsigned short* __restrict__ cB, const unsigned short* __restrict__ eB,
    const unsigned short* __restrict__ ehrTm, const int* __restrict__ em,
    unsigned short* __restrict__ attc) {
  __shared__ unsigned short SLOT[3 * 8192];
  __shared__ unsigned short S4[16384];
  const int tid = threadIdx.x, fid = blockIdx.x;
  const int lid = (fid & 7) * 32 + (fid >> 3);  // b-pairs share an XCD L2
  const int b = lid >> 1, m0 = (lid & 1) * 128;
  attn_body<8>(SLOT, S4, cB + ((long)b * LC + m0) * DD, eB + (long)b * LE * DD,
               ehrTm + (long)b * DD * LE, LE, em + (long)b * LE,
               attc + ((long)b * LC + m0) * DD, tid);
}

__global__ __launch_bounds__(512, 2) void attn_e_fused(
    const unsigned short* __restrict__ cB, const unsigned short* __restrict__ eB,
    const unsigned short* __restrict__ critTm, const int* __restrict__ cm,
    unsigned short* __restrict__ atte) {
  __shared__ unsigned short SLOT[3 * 8192];
  __shared__ unsigned short S4[16384];
  const int tid = threadIdx.x, fid = blockIdx.x;
  const int lid = (fid & 7) * 128 + (fid >> 3);  // same b->XCD mapping as c-side
  const int b = lid >> 3, n0 = (lid & 7) * 128;
  attn_body<2>(SLOT, S4, eB + ((long)b * LE + n0) * DD, cB + (long)b * LC * DD,
               critTm + (long)b * DD * LC, LC, cm + (long)b * LC,
               atte + ((long)b * LE + n0) * DD, tid);
}

// ---- r = sum_seq relu([att | origB] @ Wr + br), counted-vmcnt pipeline ----
__global__ __launch_bounds__(256, 2) void rsum_mfma(const unsigned short* __restrict__ att,
                                                    const unsigned short* __restrict__ origB,
                                                    const unsigned short* __restrict__ WrT,
                                                    const float* __restrict__ br,
                                                    float* __restrict__ rout, int Lseq) {
  __shared__ unsigned short SL[3 * 8192];
  __shared__ float red[2][128];
  const int tid = threadIdx.x, lane = tid & 63, w = tid >> 6, wm = w >> 1, wn = w & 1;
  const long m0 = (long)blockIdx.y * 128;
  const int n0 = blockIdx.x * 128;
  const int b = (int)(m0 / Lseq);
  f32x4 acc[4][4] = {};
  // prologue: steps 0,1 (8 loads outstanding; 4 per step)
  stg128_256(SL, att + m0 * DD, DD, tid);
  stg128_256(SL + 4096, WrT + (long)n0 * 512, 512, tid);
  stg128_256(SL + 8192, att + m0 * DD + 32, DD, tid);
  stg128_256(SL + 8192 + 4096, WrT + (long)n0 * 512 + 32, 512, tid);
#pragma unroll
  for (int s = 0; s < 16; ++s) {
    if (s == 15) asm volatile("s_waitcnt vmcnt(0) lgkmcnt(0)" ::: "memory");
    else         asm volatile("s_waitcnt vmcnt(4) lgkmcnt(0)" ::: "memory");
    __builtin_amdgcn_s_barrier();
    if (s < 14) {
      const int k1 = (s + 2) * 32;
      const unsigned short* aS =
          (k1 < DD) ? att + m0 * DD + k1 : origB + m0 * DD + (k1 - DD);
      unsigned short* d = SL + ((s + 2) % 3) * 8192;
      stg128_256(d, aS, DD, tid);
      stg128_256(d + 4096, WrT + (long)n0 * 512 + k1, 512, tid);
    }
    const unsigned short* base = SL + (s % 3) * 8192;
    mma_step(base, base + 4096, acc, wm, wn, lane);
  }
  const int lm = lane & 15, quad = lane >> 4;
#pragma unroll
  for (int j = 0; j < 4; ++j) {
    int col = n0 + wn * 64 + j * 16 + lm;
    float bias = br[col];
    float s = 0.f;
#pragma unroll
    for (int i = 0; i < 4; ++i)
#pragma unroll
      for (int r = 0; r < 4; ++r) {
        float v = acc[i][j][r] + bias;
        s += v > 0.f ? v : 0.f;
      }
    s += __shfl_xor(s, 16);
    s += __shfl_xor(s, 32);
    if (quad == 0) red[wm][wn * 64 + j * 16 + lm] = s;
  }
  __syncthreads();
  if (tid < 128)
    atomicAdd(&rout[b * DD + n0 + tid], red[0][tid] + red[1][tid]);
}

// ---- build m = [r1 | r2 | r1*r2 | r1-r2] as bf16 [128][1024] ----
__global__ void mbuild_kernel(const float* __restrict__ r1, const float* __restrict__ r2,
                              unsigned short* __restrict__ mB) {
  int i = blockIdx.x * 256 + threadIdx.x;
  int b = i >> 8, d = i & 255;
  float v1 = r1[i], v2 = r2[i];
  unsigned short* row = mB + (long)b * 1024;
  row[d] = f2bfu(v1);
  row[256 + d] = f2bfu(v2);
  row[512 + d] = f2bfu(v1 * v2);
  row[768 + d] = f2bfu(v1 - v2);
}

// ---- h = relu(m @ Wm + bm): M=128, N=512, K=1024 MFMA GEMM ----
__global__ __launch_bounds__(256, 2) void mlp_mfma(const unsigned short* __restrict__ mB,
                                                   const float* __restrict__ Wm,
                                                   const float* __restrict__ bm,
                                                   float* __restrict__ h) {
  __shared__ unsigned short As[4096], Bs[4096];
  const int tid = threadIdx.x, lane = tid & 63, w = tid >> 6, wm = w >> 1, wn = w & 1;
  const int n0 = blockIdx.x * 128;
  f32x4 acc[4][4] = {};
  for (int k0 = 0; k0 < 4 * DD; k0 += 32) {
    stg128_256(As, mB + k0, 1024, tid);
    {
      const int dcc = tid & 7, er = tid >> 3;
#pragma unroll
      for (int i = 0; i < 4; ++i) {
        int nch = dcc + i * 8;
        float4 v = *(const float4*)(Wm + (long)(k0 + er) * MM + n0 + nch * 4);
        float vv[4] = {v.x, v.y, v.z, v.w};
#pragma unroll
        for (int q = 0; q < 4; ++q)
          Bs[lx(nch * 4 + q, er >> 3) + (er & 7)] = f2bfu(vv[q]);
      }
    }
    __syncthreads();
    mma_step(As, Bs, acc, wm, wn, lane);
    __syncthreads();
  }
  const int lm = lane & 15, quad = lane >> 4;
#pragma unroll
  for (int i = 0; i < 4; ++i)
#pragma unroll
    for (int j = 0; j < 4; ++j) {
      int col = n0 + wn * 64 + j * 16 + lm;
      float bias = bm[col];
#pragma unroll
      for (int r = 0; r < 4; ++r) {
        int row = wm * 64 + i * 16 + quad * 4 + r;
        float v = acc[i][j][r] + bias;
        h[(long)row * MM + col] = v > 0.f ? v : 0.f;
      }
    }
}

// ---- out = h @ Wo + bo ----
__global__ void out3_kernel(const float* __restrict__ h, const float* __restrict__ Wo,
                            const float* __restrict__ bo, float* __restrict__ out) {
  const int b = blockIdx.x, tid = threadIdx.x;
  __shared__ float red[256];
  float a[3] = {0.f, 0.f, 0.f};
  for (int k = tid; k < MM; k += 256) {
    float hv = h[(long)b * MM + k];
    a[0] += hv * Wo[k * 3 + 0];
    a[1] += hv * Wo[k * 3 + 1];
    a[2] += hv * Wo[k * 3 + 2];
  }
#pragma unroll
  for (int o = 0; o < 3; ++o) {
    red[tid] = a[o]; __syncthreads();
    for (int st = 128; st > 0; st >>= 1) {
      if (tid < st) red[tid] += red[tid + st];
      __syncthreads();
    }
    if (tid == 0) out[b * 3 + o] = red[0] + bo[o];
    __syncthreads();
  }
}

extern "C" void kernel_launch(void* const* d_in, const int* in_sizes, int n_in,
                              void* d_out, int out_size, void* d_ws, size_t ws_size,
                              hipStream_t stream) {
  const float* criteria = (const float*)d_in[0];
  const float* ehr      = (const float*)d_in[1];
  const int*   cmask    = (const int*)d_in[2];
  const int*   emask    = (const int*)d_in[3];
  const float* Wa       = (const float*)d_in[4];
  const float* ba       = (const float*)d_in[5];
  const float* Wr       = (const float*)d_in[6];
  const float* br       = (const float*)d_in[7];
  const float* Wm       = (const float*)d_in[8];
  const float* bm       = (const float*)d_in[9];
  const float* Wo       = (const float*)d_in[10];
  const float* bo       = (const float*)d_in[11];
  float* out = (float*)d_out;

  char* ws = (char*)d_ws;
  unsigned short* cB     = (unsigned short*)(ws);               // 16.78 MB
  unsigned short* eB     = (unsigned short*)(ws + 16777216);    // 67.1 MB
  unsigned short* ehrTm  = (unsigned short*)(ws + 83886080);    // 67.1 MB, em-masked ehr^T
  unsigned short* critTm = (unsigned short*)(ws + 150994944);   // 16.78 MB, cm-masked crit^T
  unsigned short* ehrN   = (unsigned short*)(ws + 167772160);   // 67.1 MB natural bf16 ehr
  unsigned short* critN  = (unsigned short*)(ws + 234881024);   // 16.78 MB natural bf16 crit
  unsigned short* attc   = (unsigned short*)(ws + 251658240);   // 16.78 MB
  unsigned short* atteP  = (unsigned short*)(ws + 268435456);   // 67.1 MB
  float* r1   = (float*)(ws + 335544320);                       // 131072 B
  float* r2   = (float*)(ws + 335675392);                       // 131072 B
  unsigned short* WaT = (unsigned short*)(ws + 335806464);      // 131072 B
  unsigned short* WrT = (unsigned short*)(ws + 335937536);      // 262144 B
  unsigned short* mB  = (unsigned short*)(ws + 336199680);      // 262144 B
  float* hbuf         = (float*)(ws + 336461824);               // 262144 B

  dim3 blk(256);
  zero_kernel<<<dim3(256), blk, 0, stream>>>(r1, 65536);
  wconv_kernel<<<dim3(512), blk, 0, stream>>>(Wa, Wr, WaT, WrT);
  transT_kernel<<<dim3(DD / 64, LE / 64, BB), blk, 0, stream>>>(ehr, emask, ehrTm, ehrN, LE, DD);
  transT_kernel<<<dim3(DD / 64, LC / 64, BB), blk, 0, stream>>>(criteria, cmask, critTm, critN, LC, DD);
  proj_mfma<<<dim3(2, (BB * LC) / 128), blk, 0, stream>>>(criteria, WaT, ba, cB);
  proj_mfma<<<dim3(2, (BB * LE) / 128), blk, 0, stream>>>(ehr, WaT, ba, eB);
  attn_c_fused<<<dim3(256), dim3(512), 0, stream>>>(cB, eB, ehrTm, emask, attc);
  attn_e_fused<<<dim3(1024), dim3(512), 0, stream>>>(cB, eB, critTm, cmask, atteP);
  rsum_mfma<<<dim3(2, (BB * LC) / 128), blk, 0, stream>>>(attc, critN, WrT, br, r1, LC);
  rsum_mfma<<<dim3(2, (BB * LE) / 128), blk, 0, stream>>>(atteP, ehrN, WrT, br, r2, LE);
  mbuild_kernel<<<dim3(BB), blk, 0, stream>>>(r1, r2, mB);
  mlp_mfma<<<dim3(MM / 128), blk, 0, stream>>>(mB, Wm, bm, hbuf);
  out3_kernel<<<dim3(BB), blk, 0, stream>>>(hbuf, Wo, bo, out);
}

// Round 5
// 530.774 us; speedup vs baseline: 1.3088x; 1.1090x over previous
//
#include <hip/hip_runtime.h>
#include <hip/hip_bf16.h>

#define BB 128
#define LC 256
#define LE 1024
#define DD 256
#define MM 512

typedef short bf16x8 __attribute__((ext_vector_type(8)));
typedef unsigned short u16x8 __attribute__((ext_vector_type(8)));
typedef unsigned short u16x4 __attribute__((ext_vector_type(4)));
typedef float f32x4 __attribute__((ext_vector_type(4)));

__device__ __forceinline__ unsigned short f2bfu(float f) {
  unsigned int x = __float_as_uint(f);
  return (unsigned short)((x + 0x7fffu + ((x >> 16) & 1u)) >> 16);
}

// ---------------------------------------------------------------------------
// LDS tile layout: linear [r][32 u16] (64B rows) with 16B-chunk XOR swizzle.
// Logical chunk q of row r is STORED at chunk position q ^ ((r>>1)&3).
// b128 frag reads (16 consecutive rows, fixed q): 8 distinct 16B slots x 2
// lanes = 2-way (free). global_load_lds writes are linear so the SOURCE
// address carries the swizzle.
// ---------------------------------------------------------------------------
__device__ __forceinline__ int lx(int r, int q) {
  return r * 32 + (((q ^ ((r >> 1) & 3)) & 3) << 3);
}

__device__ __forceinline__ void gll16(const unsigned short* g, unsigned short* l) {
  __builtin_amdgcn_global_load_lds((const __attribute__((address_space(1))) void*)g,
                                   (__attribute__((address_space(3))) void*)l, 16, 0, 0);
}

// 512-thread: 128x32 tile (4096 u16), one global_load_lds per lane.
__device__ __forceinline__ void stg128(unsigned short* S, const unsigned short* g,
                                       long ldu, int tid) {
  const int l = tid & 63, w = tid >> 6;
  const int r = w * 16 + (l >> 2), q = l & 3;
  gll16(g + (long)r * ldu + (((q ^ ((r >> 1) & 3)) & 3) << 3), S + w * 512);
}

// 512-thread: 256x32 tile (8192 u16), two loads per lane.
__device__ __forceinline__ void stg256(unsigned short* S, const unsigned short* g,
                                       long ldu, int tid) {
  const int l = tid & 63, w = tid >> 6;
#pragma unroll
  for (int it = 0; it < 2; ++it) {
    const int r = it * 128 + w * 16 + (l >> 2), q = l & 3;
    gll16(g + (long)r * ldu + (((q ^ ((r >> 1) & 3)) & 3) << 3), S + it * 4096 + w * 512);
  }
}

// 256-thread: 128x32 tile, two loads per lane (4 waves).
__device__ __forceinline__ void stg128_256(unsigned short* S, const unsigned short* g,
                                           long ldu, int tid) {
  const int l = tid & 63, w = tid >> 6;
#pragma unroll
  for (int it = 0; it < 2; ++it) {
    const int r = it * 64 + w * 16 + (l >> 2), q = l & 3;
    gll16(g + (long)r * ldu + (((q ^ ((r >> 1) & 3)) & 3) << 3), S + it * 2048 + w * 512);
  }
}

// ---- 4-wave MFMA step: each wave 64x64 = 4x4 tiles of 16x16x32 ----
__device__ __forceinline__ void mma_step(const unsigned short* As, const unsigned short* Bs,
                                         f32x4 (&acc)[4][4], int wm, int wn, int lane) {
  const int lm = lane & 15, quad = lane >> 4;
  bf16x8 a[4], b[4];
#pragma unroll
  for (int i = 0; i < 4; ++i) {
    a[i] = *(const bf16x8*)&As[lx(wm * 64 + i * 16 + lm, quad)];
    b[i] = *(const bf16x8*)&Bs[lx(wn * 64 + i * 16 + lm, quad)];
  }
  __builtin_amdgcn_s_setprio(1);
#pragma unroll
  for (int i = 0; i < 4; ++i)
#pragma unroll
    for (int j = 0; j < 4; ++j)
      acc[i][j] = __builtin_amdgcn_mfma_f32_16x16x32_bf16(a[i], b[j], acc[i][j], 0, 0, 0);
  __builtin_amdgcn_s_setprio(0);
}

// ---- generic MFMA tile step with independent row offsets ----
template <int MT, int NT>
__device__ __forceinline__ void mma_tiles(const unsigned short* As, const unsigned short* Bs,
                                          f32x4 (&acc)[MT][NT], int m0, int n0, int lane) {
  const int lm = lane & 15, quad = lane >> 4;
  bf16x8 a[MT], b[NT];
#pragma unroll
  for (int i = 0; i < MT; ++i)
    a[i] = *(const bf16x8*)&As[lx(m0 + i * 16 + lm, quad)];
#pragma unroll
  for (int j = 0; j < NT; ++j)
    b[j] = *(const bf16x8*)&Bs[lx(n0 + j * 16 + lm, quad)];
  __builtin_amdgcn_s_setprio(1);
#pragma unroll
  for (int i = 0; i < MT; ++i)
#pragma unroll
    for (int j = 0; j < NT; ++j)
      acc[i][j] = __builtin_amdgcn_mfma_f32_16x16x32_bf16(a[i], b[j], acc[i][j], 0, 0, 0);
  __builtin_amdgcn_s_setprio(0);
}

// ---- zero fill ----
__global__ void zero_kernel(float* __restrict__ p, int n) {
  int i = blockIdx.x * 256 + threadIdx.x;
  if (i < n) p[i] = 0.f;
}

// ---- weight transpose+convert ----
__global__ void wconv_kernel(const float* __restrict__ Wa, const float* __restrict__ Wr,
                             unsigned short* __restrict__ WaT, unsigned short* __restrict__ WrT) {
  int i = blockIdx.x * 256 + threadIdx.x;
  if (i < 65536) WaT[i] = f2bfu(Wa[(i & 255) * 256 + (i >> 8)]);
  if (i < 131072) WrT[i] = f2bfu(Wr[(long)(i & 511) * 256 + (i >> 9)]);
}

// ---------------------------------------------------------------------------
// fp32 [R][C] -> (a) mask-baked bf16 transpose dstT[C][R], (b) natural bf16
// dstN[R][C]. Block = 256 rows x 64 cols, 256 threads.
// LDS T2[64][258] u16: bank = (c + r/2) mod 32 (258/2 = 129 === 1 mod 32).
//  - transpose-in writes (c = c4*4+k, r = rb+16i): <=4-way on 2B writes.
//  - phase-2 b128 reads (d = tid>>4 + dd*16, r = (tid&15)*8 + j*128):
//    bank start = hi + 4*lo over a wave = exact 2-way (free).
// dT global writes: 16 lanes x 16B = 256B contiguous per instruction.
// ---------------------------------------------------------------------------
__global__ void transT_kernel(const float* __restrict__ src, const int* __restrict__ mask,
                              unsigned short* __restrict__ dstT, unsigned short* __restrict__ dstN,
                              int R, int C) {
  __shared__ unsigned short T2[64 * 258];
  const int tid = threadIdx.x, b = blockIdx.z;
  const int r0 = blockIdx.y * 256, c0 = blockIdx.x * 64;
  const float* s = src + (long)b * R * C;
  const int* mk = mask + (long)b * R;
  unsigned short* dT = dstT + (long)b * R * C;
  unsigned short* dN = dstN + (long)b * R * C;
  const int c4 = tid & 15, rb = tid >> 4;
#pragma unroll
  for (int i = 0; i < 16; ++i) {
    int r = rb + i * 16;
    float4 v = *(const float4*)(s + (long)(r0 + r) * C + c0 + c4 * 4);
    u16x4 nat;
    nat[0] = f2bfu(v.x); nat[1] = f2bfu(v.y); nat[2] = f2bfu(v.z); nat[3] = f2bfu(v.w);
    *(u16x4*)(dN + (long)(r0 + r) * C + c0 + c4 * 4) = nat;
    float g = mk[r0 + r] ? 1.f : 0.f;
    T2[(c4 * 4 + 0) * 258 + r] = f2bfu(v.x * g);
    T2[(c4 * 4 + 1) * 258 + r] = f2bfu(v.y * g);
    T2[(c4 * 4 + 2) * 258 + r] = f2bfu(v.z * g);
    T2[(c4 * 4 + 3) * 258 + r] = f2bfu(v.w * g);
  }
  __syncthreads();
  const int dlo = tid >> 4, rs = (tid & 15) * 8;
#pragma unroll
  for (int dd = 0; dd < 4; ++dd) {
    const int d = dlo + dd * 16;
#pragma unroll
    for (int j = 0; j < 2; ++j) {
      const int r = rs + j * 128;
      *(u16x8*)(dT + (long)(c0 + d) * R + r0 + r) = *(const u16x8*)&T2[d * 258 + r];
    }
  }
}

// ---- proj: out = relu(AN @ Wa + ba) -> bf16. bf16 input, counted-vmcnt 3-slot ----
__global__ __launch_bounds__(256, 2) void proj_mfma(const unsigned short* __restrict__ AN,
                                                    const unsigned short* __restrict__ WaT,
                                                    const float* __restrict__ ba,
                                                    unsigned short* __restrict__ out) {
  __shared__ unsigned short SL[3 * 8192];
  const int tid = threadIdx.x, lane = tid & 63, w = tid >> 6, wm = w >> 1, wn = w & 1;
  const long m0 = (long)blockIdx.y * 128;
  const int n0 = blockIdx.x * 128;
  f32x4 acc[4][4] = {};
  stg128_256(SL, AN + m0 * DD, DD, tid);
  stg128_256(SL + 4096, WaT + (long)n0 * DD, DD, tid);
  stg128_256(SL + 8192, AN + m0 * DD + 32, DD, tid);
  stg128_256(SL + 8192 + 4096, WaT + (long)n0 * DD + 32, DD, tid);
#pragma unroll
  for (int s = 0; s < 8; ++s) {
    if (s == 7) asm volatile("s_waitcnt vmcnt(0) lgkmcnt(0)" ::: "memory");
    else        asm volatile("s_waitcnt vmcnt(4) lgkmcnt(0)" ::: "memory");
    __builtin_amdgcn_s_barrier();
    if (s < 6) {
      unsigned short* d = SL + ((s + 2) % 3) * 8192;
      stg128_256(d, AN + m0 * DD + (s + 2) * 32, DD, tid);
      stg128_256(d + 4096, WaT + (long)n0 * DD + (s + 2) * 32, DD, tid);
    }
    const unsigned short* base = SL + (s % 3) * 8192;
    mma_step(base, base + 4096, acc, wm, wn, lane);
  }
  const int lm = lane & 15, quad = lane >> 4;
#pragma unroll
  for (int i = 0; i < 4; ++i)
#pragma unroll
    for (int j = 0; j < 4; ++j) {
      int col = n0 + wn * 64 + j * 16 + lm;
      float bias = ba[col];
#pragma unroll
      for (int r = 0; r < 4; ++r) {
        long row = m0 + wm * 64 + i * 16 + quad * 4 + r;
        float v = acc[i][j][r] + bias;
        out[row * DD + col] = f2bfu(v > 0.f ? v : 0.f);
      }
    }
}

// ============================================================================
// Fused attention body (unchanged from the verified round-4 version).
// 12 steps/chunk, 3 rotating 16KB slots, 2-deep prefetch, counted
// s_waitcnt vmcnt(2) + raw s_barrier. LDS 80KB -> 2 blocks/CU.
// ============================================================================
template <int NCH>
__device__ __forceinline__ void attn_body(
    unsigned short* SLOT, unsigned short* S4,
    const unsigned short* resB, const unsigned short* aSrc,
    const unsigned short* pvB, long pvLd,
    const int* mask, unsigned short* outp, int tid) {
  const int lane = tid & 63, w = tid >> 6;
  const int lm = lane & 15, quad = lane >> 4;
  const int wmS = w >> 2, wnS = w & 3;  // S: contraction 64-half, out-row 32-quarter
  const int wm = w >> 2, wn = w & 3;    // PV: out-row 64-half, D 64-quarter
  float* asum_s = (float*)SLOT;
  f32x4 acc[4][4] = {};
  float ap0 = 0.f, ap1 = 0.f;
  stg128(SLOT, aSrc, DD, tid);
  stg128(SLOT + 4096, resB, DD, tid);
  stg128(SLOT + 8192, aSrc + 32, DD, tid);
  stg128(SLOT + 8192 + 4096, resB + 32, DD, tid);
  for (int ch = 0; ch < NCH; ++ch) {
    const unsigned short* Ag = aSrc + (long)ch * 128 * DD;
    const unsigned short* Pg = pvB + (long)ch * 128;
    f32x4 accS[4][2] = {};
#pragma unroll
    for (int s = 0; s < 8; ++s) {
      asm volatile("s_waitcnt vmcnt(2) lgkmcnt(0)" ::: "memory");
      __builtin_amdgcn_s_barrier();
      if (s < 6) {
        unsigned short* d = SLOT + ((s + 2) % 3) * 8192;
        stg128(d, Ag + (s + 2) * 32, DD, tid);
        stg128(d + 4096, resB + (s + 2) * 32, DD, tid);
      } else if (s == 6) {
        stg256(SLOT + 2 * 8192, Pg, pvLd, tid);        // PV kk=0 -> slot 2
      } else {
        stg256(SLOT, Pg + 32, pvLd, tid);              // PV kk=1 -> slot 0
      }
      const unsigned short* base = SLOT + (s % 3) * 8192;
      mma_tiles<4, 2>(base, base + 4096, accS, wmS * 64, wnS * 32, lane);
    }
    // ---- exp + pack into S4 + masked denominator partials ----
#pragma unroll
    for (int i = 0; i < 4; ++i) {
      const int A0 = wmS * 64 + i * 16 + quad * 4;
      const int4 m4 = *(const int4*)(mask + ch * 128 + A0);
      const float g0 = m4.x ? 1.f : 0.f, g1 = m4.y ? 1.f : 0.f;
      const float g2 = m4.z ? 1.f : 0.f, g3 = m4.w ? 1.f : 0.f;
      const int kk = A0 >> 5, wi = A0 & 31;
      const int qq = wi >> 3, sub = wi & 7;
#pragma unroll
      for (int j = 0; j < 2; ++j) {
        const int row = wnS * 32 + j * 16 + lm;
        float e0 = __expf(accS[i][j][0]);
        float e1 = __expf(accS[i][j][1]);
        float e2 = __expf(accS[i][j][2]);
        float e3 = __expf(accS[i][j][3]);
        float sm = g0 * e0 + g1 * e1 + g2 * e2 + g3 * e3;
        if (j == 0) ap0 += sm; else ap1 += sm;
        u16x4 pk;
        pk[0] = f2bfu(e0); pk[1] = f2bfu(e1); pk[2] = f2bfu(e2); pk[3] = f2bfu(e3);
        *(u16x4*)&S4[kk * 4096 + row * 32 + ((qq ^ ((row >> 1) & 3)) << 3) + sub] = pk;
      }
    }
#pragma unroll
    for (int kk = 0; kk < 4; ++kk) {
      if ((kk == 3) && (ch == NCH - 1))
        asm volatile("s_waitcnt vmcnt(0) lgkmcnt(0)" ::: "memory");
      else
        asm volatile("s_waitcnt vmcnt(2) lgkmcnt(0)" ::: "memory");
      __builtin_amdgcn_s_barrier();
      if (kk < 2) {
        stg256(SLOT + ((kk + 1) % 3) * 8192, Pg + (kk + 2) * 32, pvLd, tid);
      } else if (ch + 1 < NCH) {
        unsigned short* d = SLOT + (kk - 2) * 8192;    // kk=2 -> slot0, kk=3 -> slot1
        stg128(d, aSrc + (long)(ch + 1) * 128 * DD + (kk - 2) * 32, DD, tid);
        stg128(d + 4096, resB + (kk - 2) * 32, DD, tid);
      }
      mma_tiles<4, 4>(S4 + kk * 4096, SLOT + ((kk + 2) % 3) * 8192, acc,
                      wm * 64, wn * 64, lane);
    }
  }
  // ---- block-local softmax denominators ----
  if (tid < 128) asum_s[tid] = 0.f;
  __syncthreads();
  {
    float s = ap0;
    s += __shfl_xor(s, 16); s += __shfl_xor(s, 32);
    if (quad == 0) atomicAdd(&asum_s[wnS * 32 + lm], s);
    float t = ap1;
    t += __shfl_xor(t, 16); t += __shfl_xor(t, 32);
    if (quad == 0) atomicAdd(&asum_s[wnS * 32 + 16 + lm], t);
  }
  __syncthreads();
  float rs[4][4];
#pragma unroll
  for (int i = 0; i < 4; ++i)
#pragma unroll
    for (int r = 0; r < 4; ++r)
      rs[i][r] = 1.f / asum_s[wm * 64 + i * 16 + quad * 4 + r];
#pragma unroll
  for (int i = 0; i < 4; ++i)
#pragma unroll
    for (int j = 0; j < 4; ++j) {
      int col = wn * 64 + j * 16 + lm;
#pragma unroll
      for (int r = 0; r < 4; ++r) {
        int row = wm * 64 + i * 16 + quad * 4 + r;
        outp[(long)row * DD + col] = f2bfu(acc[i][j][r] * rs[i][r]);
      }
    }
}

// Merged: c-side blocks [0,256) dispatched first (4x work each), e-side
// backfills. Same b->XCD mapping on both sides so a batch's cB/eB panels
// stay in one XCD L2. Both paths share LDS; regalloc = max of paths.
__global__ __launch_bounds__(512, 2) void attn_fused(
    const unsigned short* __restrict__ cB, const unsigned short* __restrict__ eB,
    const unsigned short* __restrict__ ehrTm, const unsigned short* __restrict__ critTm,
    const int* __restrict__ em, const int* __restrict__ cm,
    unsigned short* __restrict__ attc, unsigned short* __restrict__ atte) {
  __shared__ unsigned short SLOT[3 * 8192];
  __shared__ unsigned short S4[16384];
  const int tid = threadIdx.x, fid = blockIdx.x;
  if (fid < 256) {
    const int lid = (fid & 7) * 32 + (fid >> 3);
    const int b = lid >> 1, m0 = (lid & 1) * 128;
    attn_body<8>(SLOT, S4, cB + ((long)b * LC + m0) * DD, eB + (long)b * LE * DD,
                 ehrTm + (long)b * DD * LE, LE, em + (long)b * LE,
                 attc + ((long)b * LC + m0) * DD, tid);
  } else {
    const int f = fid - 256;
    const int lid = (f & 7) * 128 + (f >> 3);
    const int b = lid >> 3, n0 = (lid & 7) * 128;
    attn_body<2>(SLOT, S4, eB + ((long)b * LE + n0) * DD, cB + (long)b * LC * DD,
                 critTm + (long)b * DD * LC, LC, cm + (long)b * LC,
                 atte + ((long)b * LE + n0) * DD, tid);
  }
}

// ---- r = sum_seq relu([att | origB] @ Wr + br), counted-vmcnt pipeline ----
__global__ __launch_bounds__(256, 2) void rsum_mfma(const unsigned short* __restrict__ att,
                                                    const unsigned short* __restrict__ origB,
                                                    const unsigned short* __restrict__ WrT,
                                                    const float* __restrict__ br,
                                                    float* __restrict__ rout, int Lseq) {
  __shared__ unsigned short SL[3 * 8192];
  __shared__ float red[2][128];
  const int tid = threadIdx.x, lane = tid & 63, w = tid >> 6, wm = w >> 1, wn = w & 1;
  const long m0 = (long)blockIdx.y * 128;
  const int n0 = blockIdx.x * 128;
  const int b = (int)(m0 / Lseq);
  f32x4 acc[4][4] = {};
  stg128_256(SL, att + m0 * DD, DD, tid);
  stg128_256(SL + 4096, WrT + (long)n0 * 512, 512, tid);
  stg128_256(SL + 8192, att + m0 * DD + 32, DD, tid);
  stg128_256(SL + 8192 + 4096, WrT + (long)n0 * 512 + 32, 512, tid);
#pragma unroll
  for (int s = 0; s < 16; ++s) {
    if (s == 15) asm volatile("s_waitcnt vmcnt(0) lgkmcnt(0)" ::: "memory");
    else         asm volatile("s_waitcnt vmcnt(4) lgkmcnt(0)" ::: "memory");
    __builtin_amdgcn_s_barrier();
    if (s < 14) {
      const int k1 = (s + 2) * 32;
      const unsigned short* aS =
          (k1 < DD) ? att + m0 * DD + k1 : origB + m0 * DD + (k1 - DD);
      unsigned short* d = SL + ((s + 2) % 3) * 8192;
      stg128_256(d, aS, DD, tid);
      stg128_256(d + 4096, WrT + (long)n0 * 512 + k1, 512, tid);
    }
    const unsigned short* base = SL + (s % 3) * 8192;
    mma_step(base, base + 4096, acc, wm, wn, lane);
  }
  const int lm = lane & 15, quad = lane >> 4;
#pragma unroll
  for (int j = 0; j < 4; ++j) {
    int col = n0 + wn * 64 + j * 16 + lm;
    float bias = br[col];
    float s = 0.f;
#pragma unroll
    for (int i = 0; i < 4; ++i)
#pragma unroll
      for (int r = 0; r < 4; ++r) {
        float v = acc[i][j][r] + bias;
        s += v > 0.f ? v : 0.f;
      }
    s += __shfl_xor(s, 16);
    s += __shfl_xor(s, 32);
    if (quad == 0) red[wm][wn * 64 + j * 16 + lm] = s;
  }
  __syncthreads();
  if (tid < 128)
    atomicAdd(&rout[b * DD + n0 + tid], red[0][tid] + red[1][tid]);
}

// ---- build m = [r1 | r2 | r1*r2 | r1-r2] as bf16 [128][1024] ----
__global__ void mbuild_kernel(const float* __restrict__ r1, const float* __restrict__ r2,
                              unsigned short* __restrict__ mB) {
  int i = blockIdx.x * 256 + threadIdx.x;
  int b = i >> 8, d = i & 255;
  float v1 = r1[i], v2 = r2[i];
  unsigned short* row = mB + (long)b * 1024;
  row[d] = f2bfu(v1);
  row[256 + d] = f2bfu(v2);
  row[512 + d] = f2bfu(v1 * v2);
  row[768 + d] = f2bfu(v1 - v2);
}

// ---- h += m @ Wm (K-split x4, atomic accumulate; bias+relu in out3) ----
__global__ __launch_bounds__(256, 2) void mlp_mfma(const unsigned short* __restrict__ mB,
                                                   const float* __restrict__ Wm,
                                                   float* __restrict__ h) {
  __shared__ unsigned short As[4096], Bs[4096];
  const int tid = threadIdx.x, lane = tid & 63, w = tid >> 6, wm = w >> 1, wn = w & 1;
  const int n0 = blockIdx.x * 128;
  const int kb = blockIdx.y * 256;
  f32x4 acc[4][4] = {};
  for (int k0 = kb; k0 < kb + 256; k0 += 32) {
    stg128_256(As, mB + k0, 1024, tid);
    {
      const int dcc = tid & 7, er = tid >> 3;
#pragma unroll
      for (int i = 0; i < 4; ++i) {
        int nch = dcc + i * 8;
        float4 v = *(const float4*)(Wm + (long)(k0 + er) * MM + n0 + nch * 4);
        float vv[4] = {v.x, v.y, v.z, v.w};
#pragma unroll
        for (int q = 0; q < 4; ++q)
          Bs[lx(nch * 4 + q, er >> 3) + (er & 7)] = f2bfu(vv[q]);
      }
    }
    __syncthreads();
    mma_step(As, Bs, acc, wm, wn, lane);
    __syncthreads();
  }
  const int lm = lane & 15, quad = lane >> 4;
#pragma unroll
  for (int i = 0; i < 4; ++i)
#pragma unroll
    for (int j = 0; j < 4; ++j) {
      int col = n0 + wn * 64 + j * 16 + lm;
#pragma unroll
      for (int r = 0; r < 4; ++r) {
        int row = wm * 64 + i * 16 + quad * 4 + r;
        atomicAdd(&h[(long)row * MM + col], acc[i][j][r]);
      }
    }
}

// ---- out = relu(h + bm) @ Wo + bo ----
__global__ void out3_kernel(const float* __restrict__ h, const float* __restrict__ Wo,
                            const float* __restrict__ bm, const float* __restrict__ bo,
                            float* __restrict__ out) {
  const int b = blockIdx.x, tid = threadIdx.x, lane = tid & 63, w = tid >> 6;
  __shared__ float red[4][3];
  float a[3] = {0.f, 0.f, 0.f};
  for (int k = tid; k < MM; k += 256) {
    float hv = h[(long)b * MM + k] + bm[k];
    hv = hv > 0.f ? hv : 0.f;
    a[0] += hv * Wo[k * 3 + 0];
    a[1] += hv * Wo[k * 3 + 1];
    a[2] += hv * Wo[k * 3 + 2];
  }
#pragma unroll
  for (int o = 0; o < 3; ++o) {
    a[o] += __shfl_xor(a[o], 1);  a[o] += __shfl_xor(a[o], 2);
    a[o] += __shfl_xor(a[o], 4);  a[o] += __shfl_xor(a[o], 8);
    a[o] += __shfl_xor(a[o], 16); a[o] += __shfl_xor(a[o], 32);
    if (lane == 0) red[w][o] = a[o];
  }
  __syncthreads();
  if (tid < 3)
    out[b * 3 + tid] = red[0][tid] + red[1][tid] + red[2][tid] + red[3][tid] + bo[tid];
}

extern "C" void kernel_launch(void* const* d_in, const int* in_sizes, int n_in,
                              void* d_out, int out_size, void* d_ws, size_t ws_size,
                              hipStream_t stream) {
  const float* criteria = (const float*)d_in[0];
  const float* ehr      = (const float*)d_in[1];
  const int*   cmask    = (const int*)d_in[2];
  const int*   emask    = (const int*)d_in[3];
  const float* Wa       = (const float*)d_in[4];
  const float* ba       = (const float*)d_in[5];
  const float* Wr       = (const float*)d_in[6];
  const float* br       = (const float*)d_in[7];
  const float* Wm       = (const float*)d_in[8];
  const float* bm       = (const float*)d_in[9];
  const float* Wo       = (const float*)d_in[10];
  const float* bo       = (const float*)d_in[11];
  float* out = (float*)d_out;

  char* ws = (char*)d_ws;
  unsigned short* cB     = (unsigned short*)(ws);               // 16.78 MB
  unsigned short* eB     = (unsigned short*)(ws + 16777216);    // 67.1 MB
  unsigned short* ehrTm  = (unsigned short*)(ws + 83886080);    // 67.1 MB, em-masked ehr^T
  unsigned short* critTm = (unsigned short*)(ws + 150994944);   // 16.78 MB, cm-masked crit^T
  unsigned short* ehrN   = (unsigned short*)(ws + 167772160);   // 67.1 MB natural bf16 ehr
  unsigned short* critN  = (unsigned short*)(ws + 234881024);   // 16.78 MB natural bf16 crit
  unsigned short* attc   = (unsigned short*)(ws + 251658240);   // 16.78 MB
  unsigned short* atteP  = (unsigned short*)(ws + 268435456);   // 67.1 MB
  float* r1   = (float*)(ws + 335544320);                       // 131072 B
  float* r2   = (float*)(ws + 335675392);                       // 131072 B
  float* hbuf = (float*)(ws + 335806464);                       // 262144 B
  unsigned short* WaT = (unsigned short*)(ws + 336068608);      // 131072 B
  unsigned short* WrT = (unsigned short*)(ws + 336199680);      // 262144 B
  unsigned short* mB  = (unsigned short*)(ws + 336461824);      // 262144 B
  // end: 336,723,968 bytes

  dim3 blk(256);
  // zero r1+r2+hbuf (contiguous, 131072 floats)
  zero_kernel<<<dim3(512), blk, 0, stream>>>(r1, 131072);
  wconv_kernel<<<dim3(512), blk, 0, stream>>>(Wa, Wr, WaT, WrT);
  transT_kernel<<<dim3(DD / 64, LE / 256, BB), blk, 0, stream>>>(ehr, emask, ehrTm, ehrN, LE, DD);
  transT_kernel<<<dim3(DD / 64, LC / 256, BB), blk, 0, stream>>>(criteria, cmask, critTm, critN, LC, DD);
  proj_mfma<<<dim3(2, (BB * LC) / 128), blk, 0, stream>>>(critN, WaT, ba, cB);
  proj_mfma<<<dim3(2, (BB * LE) / 128), blk, 0, stream>>>(ehrN, WaT, ba, eB);
  attn_fused<<<dim3(1280), dim3(512), 0, stream>>>(cB, eB, ehrTm, critTm, emask, cmask,
                                                   attc, atteP);
  rsum_mfma<<<dim3(2, (BB * LC) / 128), blk, 0, stream>>>(attc, critN, WrT, br, r1, LC);
  rsum_mfma<<<dim3(2, (BB * LE) / 128), blk, 0, stream>>>(atteP, ehrN, WrT, br, r2, LE);
  mbuild_kernel<<<dim3(BB), blk, 0, stream>>>(r1, r2, mB);
  mlp_mfma<<<dim3(MM / 128, 4), blk, 0, stream>>>(mB, Wm, hbuf);
  out3_kernel<<<dim3(BB), blk, 0, stream>>>(hbuf, Wo, bm, bo, out);
}

// Round 6
// 521.811 us; speedup vs baseline: 1.3312x; 1.0172x over previous
//
#include <hip/hip_runtime.h>
#include <hip/hip_bf16.h>

#define BB 128
#define LC 256
#define LE 1024
#define DD 256
#define MM 512

typedef short bf16x8 __attribute__((ext_vector_type(8)));
typedef unsigned short u16x8 __attribute__((ext_vector_type(8)));
typedef unsigned short u16x4 __attribute__((ext_vector_type(4)));
typedef float f32x4 __attribute__((ext_vector_type(4)));

__device__ __forceinline__ unsigned short f2bfu(float f) {
  unsigned int x = __float_as_uint(f);
  return (unsigned short)((x + 0x7fffu + ((x >> 16) & 1u)) >> 16);
}

// ---------------------------------------------------------------------------
// LDS tile layout: linear [r][32 u16] (64B rows) with 16B-chunk XOR swizzle.
// Logical chunk q of row r is STORED at chunk position q ^ ((r>>1)&3).
// b128 frag reads (16 consecutive rows, fixed q): 8 distinct 16B slots x 2
// lanes = 2-way (free). global_load_lds writes are linear so the SOURCE
// address carries the swizzle.
// ---------------------------------------------------------------------------
__device__ __forceinline__ int lx(int r, int q) {
  return r * 32 + (((q ^ ((r >> 1) & 3)) & 3) << 3);
}

__device__ __forceinline__ void gll16(const unsigned short* g, unsigned short* l) {
  __builtin_amdgcn_global_load_lds((const __attribute__((address_space(1))) void*)g,
                                   (__attribute__((address_space(3))) void*)l, 16, 0, 0);
}

// 512-thread: 128x32 tile (4096 u16), one global_load_lds per lane.
__device__ __forceinline__ void stg128(unsigned short* S, const unsigned short* g,
                                       long ldu, int tid) {
  const int l = tid & 63, w = tid >> 6;
  const int r = w * 16 + (l >> 2), q = l & 3;
  gll16(g + (long)r * ldu + (((q ^ ((r >> 1) & 3)) & 3) << 3), S + w * 512);
}

// 512-thread: 256x32 tile (8192 u16), two loads per lane.
__device__ __forceinline__ void stg256(unsigned short* S, const unsigned short* g,
                                       long ldu, int tid) {
  const int l = tid & 63, w = tid >> 6;
#pragma unroll
  for (int it = 0; it < 2; ++it) {
    const int r = it * 128 + w * 16 + (l >> 2), q = l & 3;
    gll16(g + (long)r * ldu + (((q ^ ((r >> 1) & 3)) & 3) << 3), S + it * 4096 + w * 512);
  }
}

// 256-thread: 128x32 tile, two loads per lane (4 waves).
__device__ __forceinline__ void stg128_256(unsigned short* S, const unsigned short* g,
                                           long ldu, int tid) {
  const int l = tid & 63, w = tid >> 6;
#pragma unroll
  for (int it = 0; it < 2; ++it) {
    const int r = it * 64 + w * 16 + (l >> 2), q = l & 3;
    gll16(g + (long)r * ldu + (((q ^ ((r >> 1) & 3)) & 3) << 3), S + it * 2048 + w * 512);
  }
}

// ---- 4-wave MFMA step: each wave 64x64 = 4x4 tiles of 16x16x32 ----
__device__ __forceinline__ void mma_step(const unsigned short* As, const unsigned short* Bs,
                                         f32x4 (&acc)[4][4], int wm, int wn, int lane) {
  const int lm = lane & 15, quad = lane >> 4;
  bf16x8 a[4], b[4];
#pragma unroll
  for (int i = 0; i < 4; ++i) {
    a[i] = *(const bf16x8*)&As[lx(wm * 64 + i * 16 + lm, quad)];
    b[i] = *(const bf16x8*)&Bs[lx(wn * 64 + i * 16 + lm, quad)];
  }
  __builtin_amdgcn_s_setprio(1);
#pragma unroll
  for (int i = 0; i < 4; ++i)
#pragma unroll
    for (int j = 0; j < 4; ++j)
      acc[i][j] = __builtin_amdgcn_mfma_f32_16x16x32_bf16(a[i], b[j], acc[i][j], 0, 0, 0);
  __builtin_amdgcn_s_setprio(0);
}

// ---- generic MFMA tile step with independent row offsets ----
template <int MT, int NT>
__device__ __forceinline__ void mma_tiles(const unsigned short* As, const unsigned short* Bs,
                                          f32x4 (&acc)[MT][NT], int m0, int n0, int lane) {
  const int lm = lane & 15, quad = lane >> 4;
  bf16x8 a[MT], b[NT];
#pragma unroll
  for (int i = 0; i < MT; ++i)
    a[i] = *(const bf16x8*)&As[lx(m0 + i * 16 + lm, quad)];
#pragma unroll
  for (int j = 0; j < NT; ++j)
    b[j] = *(const bf16x8*)&Bs[lx(n0 + j * 16 + lm, quad)];
  __builtin_amdgcn_s_setprio(1);
#pragma unroll
  for (int i = 0; i < MT; ++i)
#pragma unroll
    for (int j = 0; j < NT; ++j)
      acc[i][j] = __builtin_amdgcn_mfma_f32_16x16x32_bf16(a[i], b[j], acc[i][j], 0, 0, 0);
  __builtin_amdgcn_s_setprio(0);
}

// ---- zero fill ----
__global__ void zero_kernel(float* __restrict__ p, int n) {
  int i = blockIdx.x * 256 + threadIdx.x;
  if (i < n) p[i] = 0.f;
}

// ---- weight transpose+convert ----
__global__ void wconv_kernel(const float* __restrict__ Wa, const float* __restrict__ Wr,
                             unsigned short* __restrict__ WaT, unsigned short* __restrict__ WrT) {
  int i = blockIdx.x * 256 + threadIdx.x;
  if (i < 65536) WaT[i] = f2bfu(Wa[(i & 255) * 256 + (i >> 8)]);
  if (i < 131072) WrT[i] = f2bfu(Wr[(long)(i & 511) * 256 + (i >> 9)]);
}

// ---------------------------------------------------------------------------
// fp32 [R][C] -> (a) mask-baked bf16 transpose dstT[C][R], (b) natural bf16
// dstN[R][C]. Block = 256 rows x 64 cols, 256 threads. T2[64][258].
// ---------------------------------------------------------------------------
__global__ void transT_kernel(const float* __restrict__ src, const int* __restrict__ mask,
                              unsigned short* __restrict__ dstT, unsigned short* __restrict__ dstN,
                              int R, int C) {
  __shared__ unsigned short T2[64 * 258];
  const int tid = threadIdx.x, b = blockIdx.z;
  const int r0 = blockIdx.y * 256, c0 = blockIdx.x * 64;
  const float* s = src + (long)b * R * C;
  const int* mk = mask + (long)b * R;
  unsigned short* dT = dstT + (long)b * R * C;
  unsigned short* dN = dstN + (long)b * R * C;
  const int c4 = tid & 15, rb = tid >> 4;
#pragma unroll
  for (int i = 0; i < 16; ++i) {
    int r = rb + i * 16;
    float4 v = *(const float4*)(s + (long)(r0 + r) * C + c0 + c4 * 4);
    u16x4 nat;
    nat[0] = f2bfu(v.x); nat[1] = f2bfu(v.y); nat[2] = f2bfu(v.z); nat[3] = f2bfu(v.w);
    *(u16x4*)(dN + (long)(r0 + r) * C + c0 + c4 * 4) = nat;
    float g = mk[r0 + r] ? 1.f : 0.f;
    T2[(c4 * 4 + 0) * 258 + r] = f2bfu(v.x * g);
    T2[(c4 * 4 + 1) * 258 + r] = f2bfu(v.y * g);
    T2[(c4 * 4 + 2) * 258 + r] = f2bfu(v.z * g);
    T2[(c4 * 4 + 3) * 258 + r] = f2bfu(v.w * g);
  }
  __syncthreads();
  const int dlo = tid >> 4, rs = (tid & 15) * 8;
#pragma unroll
  for (int dd = 0; dd < 4; ++dd) {
    const int d = dlo + dd * 16;
#pragma unroll
    for (int j = 0; j < 2; ++j) {
      const int r = rs + j * 128;
      *(u16x8*)(dT + (long)(c0 + d) * R + r0 + r) = *(const u16x8*)&T2[d * 258 + r];
    }
  }
}

// ---- proj: out = relu(AN @ Wa + ba) -> bf16. bf16 input, counted-vmcnt 3-slot ----
__global__ __launch_bounds__(256, 2) void proj_mfma(const unsigned short* __restrict__ AN,
                                                    const unsigned short* __restrict__ WaT,
                                                    const float* __restrict__ ba,
                                                    unsigned short* __restrict__ out) {
  __shared__ unsigned short SL[3 * 8192];
  const int tid = threadIdx.x, lane = tid & 63, w = tid >> 6, wm = w >> 1, wn = w & 1;
  const long m0 = (long)blockIdx.y * 128;
  const int n0 = blockIdx.x * 128;
  f32x4 acc[4][4] = {};
  stg128_256(SL, AN + m0 * DD, DD, tid);
  stg128_256(SL + 4096, WaT + (long)n0 * DD, DD, tid);
  stg128_256(SL + 8192, AN + m0 * DD + 32, DD, tid);
  stg128_256(SL + 8192 + 4096, WaT + (long)n0 * DD + 32, DD, tid);
#pragma unroll
  for (int s = 0; s < 8; ++s) {
    if (s == 7) asm volatile("s_waitcnt vmcnt(0) lgkmcnt(0)" ::: "memory");
    else        asm volatile("s_waitcnt vmcnt(4) lgkmcnt(0)" ::: "memory");
    __builtin_amdgcn_s_barrier();
    if (s < 6) {
      unsigned short* d = SL + ((s + 2) % 3) * 8192;
      stg128_256(d, AN + m0 * DD + (s + 2) * 32, DD, tid);
      stg128_256(d + 4096, WaT + (long)n0 * DD + (s + 2) * 32, DD, tid);
    }
    const unsigned short* base = SL + (s % 3) * 8192;
    mma_step(base, base + 4096, acc, wm, wn, lane);
  }
  const int lm = lane & 15, quad = lane >> 4;
#pragma unroll
  for (int i = 0; i < 4; ++i)
#pragma unroll
    for (int j = 0; j < 4; ++j) {
      int col = n0 + wn * 64 + j * 16 + lm;
      float bias = ba[col];
#pragma unroll
      for (int r = 0; r < 4; ++r) {
        long row = m0 + wm * 64 + i * 16 + quad * 4 + r;
        float v = acc[i][j][r] + bias;
        out[row * DD + col] = f2bfu(v > 0.f ? v : 0.f);
      }
    }
}

// ============================================================================
// Fused attention body — DEPTH-5 pipeline. 12 steps/chunk (8 S + 4 PV),
// each step stages exactly 2 global_load_lds/thread. 6 rotating 16KB slots,
// prefetch distance 5, steady-state s_waitcnt vmcnt(8) (4 steps in flight).
// Stage at step t targets slot (t+5)%6 == (t-1)%6: its readers finished
// before barrier t (per-wave lgkmcnt(0) precedes the barrier). Last chunk
// tapers vmcnt 8->6->4->2->0 over s=8..11 and skips dead stages.
// LDS: 6*16KB slots + 32KB S4 = 128KB -> 1 block/CU (8 waves).
// ============================================================================
template <int NCH>
__device__ __forceinline__ void attn_body(
    unsigned short* SLOT, unsigned short* S4,
    const unsigned short* resB, const unsigned short* aSrc,
    const unsigned short* pvB, long pvLd,
    const int* mask, unsigned short* outp, int tid) {
  const int lane = tid & 63, w = tid >> 6;
  const int lm = lane & 15, quad = lane >> 4;
  const int wmS = w >> 2, wnS = w & 3;  // S: contraction 64-half, out-row 32-quarter
  const int wm = w >> 2, wn = w & 3;    // PV: out-row 64-half, D 64-quarter
  float* asum_s = (float*)SLOT;
  f32x4 acc[4][4] = {};
  float ap0 = 0.f, ap1 = 0.f;
  // prologue: stage steps 0..4 (S k=0..4 of chunk 0) -> slots 0..4 (10 loads)
#pragma unroll
  for (int i = 0; i < 5; ++i) {
    stg128(SLOT + i * 8192, aSrc + i * 32, DD, tid);
    stg128(SLOT + i * 8192 + 4096, resB + i * 32, DD, tid);
  }
  for (int ch = 0; ch < NCH; ++ch) {
    const unsigned short* Ag = aSrc + (long)ch * 128 * DD;
    const unsigned short* An = aSrc + (long)(ch + 1) * 128 * DD;
    const unsigned short* Pg = pvB + (long)ch * 128;
    const bool last = (ch == NCH - 1);
    f32x4 accS[4][2] = {};
    // ---- S phase: s = 0..7 ----
#pragma unroll
    for (int s = 0; s < 8; ++s) {
      asm volatile("s_waitcnt vmcnt(8) lgkmcnt(0)" ::: "memory");
      __builtin_amdgcn_s_barrier();
      if (s < 3) {
        // stage step s+5 = S k=s+5 of this chunk
        unsigned short* d = SLOT + ((s + 5) % 6) * 8192;
        stg128(d, Ag + (s + 5) * 32, DD, tid);
        stg128(d + 4096, resB + (s + 5) * 32, DD, tid);
      } else if (s < 7) {
        // stage step s+5 = PV kk=s-3 of this chunk
        stg256(SLOT + ((s + 5) % 6) * 8192, Pg + (s - 3) * 32, pvLd, tid);
      } else if (!last) {
        // s==7: stage step 12 = next chunk S k=0
        unsigned short* d = SLOT + ((s + 5) % 6) * 8192;
        stg128(d, An, DD, tid);
        stg128(d + 4096, resB, DD, tid);
      }
      const unsigned short* base = SLOT + (s % 6) * 8192;
      mma_tiles<4, 2>(base, base + 4096, accS, wmS * 64, wnS * 32, lane);
    }
    // ---- exp + pack into S4 + masked denominator partials ----
#pragma unroll
    for (int i = 0; i < 4; ++i) {
      const int A0 = wmS * 64 + i * 16 + quad * 4;
      const int4 m4 = *(const int4*)(mask + ch * 128 + A0);
      const float g0 = m4.x ? 1.f : 0.f, g1 = m4.y ? 1.f : 0.f;
      const float g2 = m4.z ? 1.f : 0.f, g3 = m4.w ? 1.f : 0.f;
      const int kk = A0 >> 5, wi = A0 & 31;
      const int qq = wi >> 3, sub = wi & 7;
#pragma unroll
      for (int j = 0; j < 2; ++j) {
        const int row = wnS * 32 + j * 16 + lm;
        float e0 = __expf(accS[i][j][0]);
        float e1 = __expf(accS[i][j][1]);
        float e2 = __expf(accS[i][j][2]);
        float e3 = __expf(accS[i][j][3]);
        float sm = g0 * e0 + g1 * e1 + g2 * e2 + g3 * e3;
        if (j == 0) ap0 += sm; else ap1 += sm;
        u16x4 pk;
        pk[0] = f2bfu(e0); pk[1] = f2bfu(e1); pk[2] = f2bfu(e2); pk[3] = f2bfu(e3);
        *(u16x4*)&S4[kk * 4096 + row * 32 + ((qq ^ ((row >> 1) & 3)) << 3) + sub] = pk;
      }
    }
    // ---- PV phase: s = 8..11 (kk = s-8) ----
#pragma unroll
    for (int kk = 0; kk < 4; ++kk) {
      if (last) {
        if (kk == 0)      asm volatile("s_waitcnt vmcnt(6) lgkmcnt(0)" ::: "memory");
        else if (kk == 1) asm volatile("s_waitcnt vmcnt(4) lgkmcnt(0)" ::: "memory");
        else if (kk == 2) asm volatile("s_waitcnt vmcnt(2) lgkmcnt(0)" ::: "memory");
        else              asm volatile("s_waitcnt vmcnt(0) lgkmcnt(0)" ::: "memory");
      } else {
        asm volatile("s_waitcnt vmcnt(8) lgkmcnt(0)" ::: "memory");
      }
      __builtin_amdgcn_s_barrier();
      if (!last) {
        // stage step (8+kk)+5 = next chunk S k=kk+1
        unsigned short* d = SLOT + ((kk + 13) % 6) * 8192;
        stg128(d, An + (kk + 1) * 32, DD, tid);
        stg128(d + 4096, resB + (kk + 1) * 32, DD, tid);
      }
      mma_tiles<4, 4>(S4 + kk * 4096, SLOT + ((kk + 8) % 6) * 8192, acc,
                      wm * 64, wn * 64, lane);
    }
  }
  // ---- block-local softmax denominators ----
  if (tid < 128) asum_s[tid] = 0.f;
  __syncthreads();
  {
    float s = ap0;
    s += __shfl_xor(s, 16); s += __shfl_xor(s, 32);
    if (quad == 0) atomicAdd(&asum_s[wnS * 32 + lm], s);
    float t = ap1;
    t += __shfl_xor(t, 16); t += __shfl_xor(t, 32);
    if (quad == 0) atomicAdd(&asum_s[wnS * 32 + 16 + lm], t);
  }
  __syncthreads();
  float rs[4][4];
#pragma unroll
  for (int i = 0; i < 4; ++i)
#pragma unroll
    for (int r = 0; r < 4; ++r)
      rs[i][r] = 1.f / asum_s[wm * 64 + i * 16 + quad * 4 + r];
#pragma unroll
  for (int i = 0; i < 4; ++i)
#pragma unroll
    for (int j = 0; j < 4; ++j) {
      int col = wn * 64 + j * 16 + lm;
#pragma unroll
      for (int r = 0; r < 4; ++r) {
        int row = wm * 64 + i * 16 + quad * 4 + r;
        outp[(long)row * DD + col] = f2bfu(acc[i][j][r] * rs[i][r]);
      }
    }
}

// Merged: c-side blocks [0,256) dispatched first (4x work each), e-side
// backfills. Same b->XCD mapping on both sides.
__global__ __launch_bounds__(512, 2) void attn_fused(
    const unsigned short* __restrict__ cB, const unsigned short* __restrict__ eB,
    const unsigned short* __restrict__ ehrTm, const unsigned short* __restrict__ critTm,
    const int* __restrict__ em, const int* __restrict__ cm,
    unsigned short* __restrict__ attc, unsigned short* __restrict__ atte) {
  __shared__ unsigned short SLOT[6 * 8192];
  __shared__ unsigned short S4[16384];
  const int tid = threadIdx.x, fid = blockIdx.x;
  if (fid < 256) {
    const int lid = (fid & 7) * 32 + (fid >> 3);
    const int b = lid >> 1, m0 = (lid & 1) * 128;
    attn_body<8>(SLOT, S4, cB + ((long)b * LC + m0) * DD, eB + (long)b * LE * DD,
                 ehrTm + (long)b * DD * LE, LE, em + (long)b * LE,
                 attc + ((long)b * LC + m0) * DD, tid);
  } else {
    const int f = fid - 256;
    const int lid = (f & 7) * 128 + (f >> 3);
    const int b = lid >> 3, n0 = (lid & 7) * 128;
    attn_body<2>(SLOT, S4, eB + ((long)b * LE + n0) * DD, cB + (long)b * LC * DD,
                 critTm + (long)b * DD * LC, LC, cm + (long)b * LC,
                 atte + ((long)b * LE + n0) * DD, tid);
  }
}

// ---- r = sum_seq relu([att | origB] @ Wr + br), counted-vmcnt pipeline ----
__global__ __launch_bounds__(256, 2) void rsum_mfma(const unsigned short* __restrict__ att,
                                                    const unsigned short* __restrict__ origB,
                                                    const unsigned short* __restrict__ WrT,
                                                    const float* __restrict__ br,
                                                    float* __restrict__ rout, int Lseq) {
  __shared__ unsigned short SL[3 * 8192];
  __shared__ float red[2][128];
  const int tid = threadIdx.x, lane = tid & 63, w = tid >> 6, wm = w >> 1, wn = w & 1;
  const long m0 = (long)blockIdx.y * 128;
  const int n0 = blockIdx.x * 128;
  const int b = (int)(m0 / Lseq);
  f32x4 acc[4][4] = {};
  stg128_256(SL, att + m0 * DD, DD, tid);
  stg128_256(SL + 4096, WrT + (long)n0 * 512, 512, tid);
  stg128_256(SL + 8192, att + m0 * DD + 32, DD, tid);
  stg128_256(SL + 8192 + 4096, WrT + (long)n0 * 512 + 32, 512, tid);
#pragma unroll
  for (int s = 0; s < 16; ++s) {
    if (s == 15) asm volatile("s_waitcnt vmcnt(0) lgkmcnt(0)" ::: "memory");
    else         asm volatile("s_waitcnt vmcnt(4) lgkmcnt(0)" ::: "memory");
    __builtin_amdgcn_s_barrier();
    if (s < 14) {
      const int k1 = (s + 2) * 32;
      const unsigned short* aS =
          (k1 < DD) ? att + m0 * DD + k1 : origB + m0 * DD + (k1 - DD);
      unsigned short* d = SL + ((s + 2) % 3) * 8192;
      stg128_256(d, aS, DD, tid);
      stg128_256(d + 4096, WrT + (long)n0 * 512 + k1, 512, tid);
    }
    const unsigned short* base = SL + (s % 3) * 8192;
    mma_step(base, base + 4096, acc, wm, wn, lane);
  }
  const int lm = lane & 15, quad = lane >> 4;
#pragma unroll
  for (int j = 0; j < 4; ++j) {
    int col = n0 + wn * 64 + j * 16 + lm;
    float bias = br[col];
    float s = 0.f;
#pragma unroll
    for (int i = 0; i < 4; ++i)
#pragma unroll
      for (int r = 0; r < 4; ++r) {
        float v = acc[i][j][r] + bias;
        s += v > 0.f ? v : 0.f;
      }
    s += __shfl_xor(s, 16);
    s += __shfl_xor(s, 32);
    if (quad == 0) red[wm][wn * 64 + j * 16 + lm] = s;
  }
  __syncthreads();
  if (tid < 128)
    atomicAdd(&rout[b * DD + n0 + tid], red[0][tid] + red[1][tid]);
}

// ---- build m = [r1 | r2 | r1*r2 | r1-r2] as bf16 [128][1024] ----
__global__ void mbuild_kernel(const float* __restrict__ r1, const float* __restrict__ r2,
                              unsigned short* __restrict__ mB) {
  int i = blockIdx.x * 256 + threadIdx.x;
  int b = i >> 8, d = i & 255;
  float v1 = r1[i], v2 = r2[i];
  unsigned short* row = mB + (long)b * 1024;
  row[d] = f2bfu(v1);
  row[256 + d] = f2bfu(v2);
  row[512 + d] = f2bfu(v1 * v2);
  row[768 + d] = f2bfu(v1 - v2);
}

// ---- h += m @ Wm (K-split x4, atomic accumulate; bias+relu in out3) ----
__global__ __launch_bounds__(256, 2) void mlp_mfma(const unsigned short* __restrict__ mB,
                                                   const float* __restrict__ Wm,
                                                   float* __restrict__ h) {
  __shared__ unsigned short As[4096], Bs[4096];
  const int tid = threadIdx.x, lane = tid & 63, w = tid >> 6, wm = w >> 1, wn = w & 1;
  const int n0 = blockIdx.x * 128;
  const int kb = blockIdx.y * 256;
  f32x4 acc[4][4] = {};
  for (int k0 = kb; k0 < kb + 256; k0 += 32) {
    stg128_256(As, mB + k0, 1024, tid);
    {
      const int dcc = tid & 7, er = tid >> 3;
#pragma unroll
      for (int i = 0; i < 4; ++i) {
        int nch = dcc + i * 8;
        float4 v = *(const float4*)(Wm + (long)(k0 + er) * MM + n0 + nch * 4);
        float vv[4] = {v.x, v.y, v.z, v.w};
#pragma unroll
        for (int q = 0; q < 4; ++q)
          Bs[lx(nch * 4 + q, er >> 3) + (er & 7)] = f2bfu(vv[q]);
      }
    }
    __syncthreads();
    mma_step(As, Bs, acc, wm, wn, lane);
    __syncthreads();
  }
  const int lm = lane & 15, quad = lane >> 4;
#pragma unroll
  for (int i = 0; i < 4; ++i)
#pragma unroll
    for (int j = 0; j < 4; ++j) {
      int col = n0 + wn * 64 + j * 16 + lm;
#pragma unroll
      for (int r = 0; r < 4; ++r) {
        int row = wm * 64 + i * 16 + quad * 4 + r;
        atomicAdd(&h[(long)row * MM + col], acc[i][j][r]);
      }
    }
}

// ---- out = relu(h + bm) @ Wo + bo ----
__global__ void out3_kernel(const float* __restrict__ h, const float* __restrict__ Wo,
                            const float* __restrict__ bm, const float* __restrict__ bo,
                            float* __restrict__ out) {
  const int b = blockIdx.x, tid = threadIdx.x, lane = tid & 63, w = tid >> 6;
  __shared__ float red[4][3];
  float a[3] = {0.f, 0.f, 0.f};
  for (int k = tid; k < MM; k += 256) {
    float hv = h[(long)b * MM + k] + bm[k];
    hv = hv > 0.f ? hv : 0.f;
    a[0] += hv * Wo[k * 3 + 0];
    a[1] += hv * Wo[k * 3 + 1];
    a[2] += hv * Wo[k * 3 + 2];
  }
#pragma unroll
  for (int o = 0; o < 3; ++o) {
    a[o] += __shfl_xor(a[o], 1);  a[o] += __shfl_xor(a[o], 2);
    a[o] += __shfl_xor(a[o], 4);  a[o] += __shfl_xor(a[o], 8);
    a[o] += __shfl_xor(a[o], 16); a[o] += __shfl_xor(a[o], 32);
    if (lane == 0) red[w][o] = a[o];
  }
  __syncthreads();
  if (tid < 3)
    out[b * 3 + tid] = red[0][tid] + red[1][tid] + red[2][tid] + red[3][tid] + bo[tid];
}

extern "C" void kernel_launch(void* const* d_in, const int* in_sizes, int n_in,
                              void* d_out, int out_size, void* d_ws, size_t ws_size,
                              hipStream_t stream) {
  const float* criteria = (const float*)d_in[0];
  const float* ehr      = (const float*)d_in[1];
  const int*   cmask    = (const int*)d_in[2];
  const int*   emask    = (const int*)d_in[3];
  const float* Wa       = (const float*)d_in[4];
  const float* ba       = (const float*)d_in[5];
  const float* Wr       = (const float*)d_in[6];
  const float* br       = (const float*)d_in[7];
  const float* Wm       = (const float*)d_in[8];
  const float* bm       = (const float*)d_in[9];
  const float* Wo       = (const float*)d_in[10];
  const float* bo       = (const float*)d_in[11];
  float* out = (float*)d_out;

  char* ws = (char*)d_ws;
  unsigned short* cB     = (unsigned short*)(ws);               // 16.78 MB
  unsigned short* eB     = (unsigned short*)(ws + 16777216);    // 67.1 MB
  unsigned short* ehrTm  = (unsigned short*)(ws + 83886080);    // 67.1 MB, em-masked ehr^T
  unsigned short* critTm = (unsigned short*)(ws + 150994944);   // 16.78 MB, cm-masked crit^T
  unsigned short* ehrN   = (unsigned short*)(ws + 167772160);   // 67.1 MB natural bf16 ehr
  unsigned short* critN  = (unsigned short*)(ws + 234881024);   // 16.78 MB natural bf16 crit
  unsigned short* attc   = (unsigned short*)(ws + 251658240);   // 16.78 MB
  unsigned short* atteP  = (unsigned short*)(ws + 268435456);   // 67.1 MB
  float* r1   = (float*)(ws + 335544320);                       // 131072 B
  float* r2   = (float*)(ws + 335675392);                       // 131072 B
  float* hbuf = (float*)(ws + 335806464);                       // 262144 B
  unsigned short* WaT = (unsigned short*)(ws + 336068608);      // 131072 B
  unsigned short* WrT = (unsigned short*)(ws + 336199680);      // 262144 B
  unsigned short* mB  = (unsigned short*)(ws + 336461824);      // 262144 B

  dim3 blk(256);
  // zero r1+r2+hbuf (contiguous, 131072 floats)
  zero_kernel<<<dim3(512), blk, 0, stream>>>(r1, 131072);
  wconv_kernel<<<dim3(512), blk, 0, stream>>>(Wa, Wr, WaT, WrT);
  transT_kernel<<<dim3(DD / 64, LE / 256, BB), blk, 0, stream>>>(ehr, emask, ehrTm, ehrN, LE, DD);
  transT_kernel<<<dim3(DD / 64, LC / 256, BB), blk, 0, stream>>>(criteria, cmask, critTm, critN, LC, DD);
  proj_mfma<<<dim3(2, (BB * LC) / 128), blk, 0, stream>>>(critN, WaT, ba, cB);
  proj_mfma<<<dim3(2, (BB * LE) / 128), blk, 0, stream>>>(ehrN, WaT, ba, eB);
  attn_fused<<<dim3(1280), dim3(512), 0, stream>>>(cB, eB, ehrTm, critTm, emask, cmask,
                                                   attc, atteP);
  rsum_mfma<<<dim3(2, (BB * LC) / 128), blk, 0, stream>>>(attc, critN, WrT, br, r1, LC);
  rsum_mfma<<<dim3(2, (BB * LE) / 128), blk, 0, stream>>>(atteP, ehrN, WrT, br, r2, LE);
  mbuild_kernel<<<dim3(BB), blk, 0, stream>>>(r1, r2, mB);
  mlp_mfma<<<dim3(MM / 128, 4), blk, 0, stream>>>(mB, Wm, hbuf);
  out3_kernel<<<dim3(BB), blk, 0, stream>>>(hbuf, Wo, bm, bo, out);
}